// Round 7
// baseline (781.810 us; speedup 1.0000x reference)
//
#include <hip/hip_runtime.h>
#include <hip/hip_cooperative_groups.h>
#include <hip/hip_bf16.h>
#include <math.h>

namespace cg = cooperative_groups;

typedef __hip_bfloat16 bf16;
typedef unsigned short ushort;
typedef unsigned int uint;
typedef unsigned long long ull;
static __device__ __forceinline__ float b2f(bf16 x){ return __bfloat162float(x); }

static __device__ __forceinline__ float ldf(const void* p, int i, int isbf){
    return isbf ? b2f(((const bf16*)p)[i]) : ((const float*)p)[i];
}
static __device__ __forceinline__ ushort f2b(float x){
    return __bfloat16_as_ushort(__float2bfloat16(x));
}
static __device__ __forceinline__ uint fcode(float v){
    uint u = __float_as_uint(v);
    return (u & 0x80000000u) ? ~u : (u | 0x80000000u);
}
static __device__ __forceinline__ float fdecode(uint c){
    uint u = (c & 0x80000000u) ? (c & 0x7FFFFFFFu) : ~c;
    return __uint_as_float(u);
}

#define NN    4096
#define FEAT0 500
#define DIN   512
#define NH    256
#define KL1   3072
#define KL2   2304
#define KL3   1728
#define EDGE_CAP 786432u
#define NTRI  2080   // 64*65/2 lower-triangle tiles at 64x64

typedef __attribute__((ext_vector_type(8)))  short v8s;
typedef __attribute__((ext_vector_type(16))) float v16f;

// async global->LDS, 16B/lane. LDS dest is wave-uniform base + lane*16;
// global src is per-lane (pre-swizzled to preserve the XOR LDS layout).
static __device__ __forceinline__ void gl_lds16(const ushort* g, ushort* l){
    __builtin_amdgcn_global_load_lds(
        (const __attribute__((address_space(1))) void*)g,
        (__attribute__((address_space(3))) void*)l, 16, 0, 0);
}

// check min(n,256) leading 16-bit halves; bf16 data here has |v|<64 (exp<135);
// fp32 misread has uniform-random exponent fields.
static __device__ __forceinline__ void detect_bf16(const void* p, int n, int t,
        uint* flag){
    if (t < 256 && t < n){
        uint e = ((uint)((const ushort*)p)[t] >> 7) & 0xFFu;
        if (e >= 135u) atomicAnd(flag, 0u);
    }
}

// ---------------- prep: pos MLP + concat + W-convert + ALL inits -----------
struct DtIn { const void* p[19]; int n[19]; };
__global__ __launch_bounds__(512) void k_prep(DtIn da,
        ushort* __restrict__ Xb, float* __restrict__ sq, ushort* __restrict__ Wb,
        unsigned* __restrict__ dflag, float* __restrict__ degA,
        uint* __restrict__ maxU, float* __restrict__ sums,
        unsigned* __restrict__ ecnt, unsigned* __restrict__ maxd2,
        float* __restrict__ tmin){
    int row = blockIdx.x, t = threadIdx.x;
    if (row < NN){
        __shared__ uint fl[4];
        if (t < 4) fl[t] = 1u;
        __syncthreads();
        detect_bf16(da.p[0], da.n[0], t, &fl[0]);   // feature
        detect_bf16(da.p[1], da.n[1], t, &fl[1]);   // img
        detect_bf16(da.p[2], da.n[2], t, &fl[2]);   // Wpos
        detect_bf16(da.p[3], da.n[3], t, &fl[3]);   // bpos
        __syncthreads();
        int f_feat = (int)fl[0], f_img = (int)fl[1], f_wp = (int)fl[2], f_bp = (int)fl[3];
        float v;
        if (t < FEAT0) v = ldf(da.p[0], row*FEAT0 + t, f_feat);
        else {
            int c = t - FEAT0;
            float acc = ldf(da.p[3], c, f_bp);
            #pragma unroll
            for (int d = 0; d < 6; d++)
                acc += ldf(da.p[1], row*6+d, f_img) * ldf(da.p[2], d*12+c, f_wp);
            v = fmaxf(acc, 0.f);
        }
        bf16 vb = __float2bfloat16(v);
        Xb[row*DIN + t] = __bfloat16_as_ushort(vb);
        float vr = b2f(vb);                 // sq of rounded vector -> d2 exact
        float vsq = vr*vr;
        #pragma unroll
        for (int off = 32; off >= 1; off >>= 1) vsq += __shfl_down(vsq, off);
        __shared__ float red[8];
        if ((t & 63) == 0) red[t >> 6] = vsq;
        __syncthreads();
        if (t == 0){
            float sres = 0.f;
            #pragma unroll
            for (int i = 0; i < 8; i++) sres += red[i];
            sq[row] = sres;
        }
    } else if (row < NN + 64){
        __shared__ uint fl[3];
        if (t < 3) fl[t] = 1u;
        __syncthreads();
        detect_bf16(da.p[4], da.n[4], t, &fl[0]);   // W1
        detect_bf16(da.p[6], da.n[6], t, &fl[1]);   // W2
        detect_bf16(da.p[8], da.n[8], t, &fl[2]);   // W3
        __syncthreads();
        int i0 = ((row - NN)*512 + t)*8;
        #pragma unroll
        for (int j = 0; j < 8; j++){
            int idx = i0 + j;
            float v;
            if (idx < 131072)       v = ldf(da.p[4], idx,          (int)fl[0]);
            else if (idx < 196608)  v = ldf(da.p[6], idx - 131072, (int)fl[1]);
            else                    v = ldf(da.p[8], idx - 196608, (int)fl[2]);
            Wb[idx] = __bfloat16_as_ushort(__float2bfloat16(v));
        }
    } else {
        for (int i = t; i < NN; i += 512) degA[i] = 1.0f;
        for (int i = t; i < 4096; i += 512) tmin[i] = INFINITY;
        for (int i = t; i < 768; i += 512){ maxU[i] = 0x007FFFFFu; sums[i] = 0.f; }
        if (t == 0){
            #pragma unroll
            for (int i = 0; i < 8; i++) ecnt[i] = 0u;
            maxd2[0] = 0u;
        }
        if (t < 19){
            const unsigned short* h = (const unsigned short*)da.p[t];
            int n = da.n[t]; if (n > 256) n = 256;
            int isbf = 1;
            for (int j = 0; j < n; j++){
                uint e = ((uint)h[j] >> 7) & 0xFFu;
                if (e >= 135u) isbf = 0;
            }
            dflag[t] = (unsigned)isbf;
        }
    }
}

// 64x64 MFMA tile of A·B^T from row-major bf16, K cols (gl_lds staging).
static __device__ __forceinline__ v16f mm_tile(const ushort* __restrict__ Arows,
        const ushort* __restrict__ Brows, int K, ushort* As, ushort* Bs,
        int tid, int wv, int l31, int hi){
    int lane = tid & 63;
    int ro = lane >> 3, cch = lane & 7;
    int r0 = wv*16 + ro, r1 = wv*16 + 8 + ro;
    const ushort* gA0 = Arows + (size_t)r0*K + ((cch ^ (r0&7))<<3);
    const ushort* gA1 = Arows + (size_t)r1*K + ((cch ^ (r1&7))<<3);
    const ushort* gB0 = Brows + (size_t)r0*K + ((cch ^ (r0&7))<<3);
    const ushort* gB1 = Brows + (size_t)r1*K + ((cch ^ (r1&7))<<3);
    ushort* lA0 = As + (wv*16)*64;
    ushort* lA1 = As + (wv*16+8)*64;
    ushort* lB0 = Bs + (wv*16)*64;
    ushort* lB1 = Bs + (wv*16+8)*64;
    int wwr = wv >> 1, wwc = wv & 1;
    int ra0 = (wwr*32 + l31)*64, rbp = (wwc*32 + l31)*64;
    int fr7a = (wwr*32 + l31) & 7, fr7b = (wwc*32 + l31) & 7;
    v16f acc = {};
    int NC = K >> 6;
    for (int c = 0; c < NC; c++){
        int k0 = c*64;
        __syncthreads();
        gl_lds16(gA0 + k0, lA0);
        gl_lds16(gA1 + k0, lA1);
        gl_lds16(gB0 + k0, lB0);
        gl_lds16(gB1 + k0, lB1);
        __syncthreads();
        #pragma unroll
        for (int ks = 0; ks < 4; ks++){
            int gq = ks*2 + hi;
            v8s a = *(const v8s*)&As[ra0 + ((gq^fr7a)<<3)];
            v8s b = *(const v8s*)&Bs[rbp + ((gq^fr7b)<<3)];
            acc = __builtin_amdgcn_mfma_f32_32x32x16_bf16(a, b, acc, 0, 0, 0);
        }
    }
    return acc;
}

// ---------------- X @ W via MFMA (bf16 input), 64x64 tile ------------------
static __device__ __forceinline__ void xw_body(const ushort* __restrict__ Ab,
        const ushort* __restrict__ Wb, float* __restrict__ XW, int rb, int cb,
        int K, ushort* As, ushort* Bs){
    int tid = threadIdx.x, lane = tid & 63, wv = tid >> 6;
    int wwr = wv >> 1, wwc = wv & 1;
    int l31 = lane & 31, hi = lane >> 5;
    int arow0 = tid >> 3, ag = tid & 7;
    int arow1 = arow0 + 32;
    int da0 = arow0*64 + ((ag^(arow0&7))<<3);
    int da1 = arow1*64 + ((ag^(arow1&7))<<3);
    const size_t baseA = (size_t)rb*64*K;
    int kr = tid >> 2, ng = tid & 3;
    float4 a0p = *(const float4*)(Ab + baseA + (size_t)arow0*K + ag*8);
    float4 a1p = *(const float4*)(Ab + baseA + (size_t)arow1*K + ag*8);
    float4 b0p = *(const float4*)(Wb + (size_t)kr*NH + cb*64 + ng*16);
    float4 b1p = *(const float4*)(Wb + (size_t)kr*NH + cb*64 + ng*16 + 8);
    v16f acc = {};
    int ra0 = (wwr*32 + l31)*64, rbp = (wwc*32 + l31)*64;
    int fr7a = (wwr*32 + l31) & 7, fr7b = (wwc*32 + l31) & 7;
    int kg = kr >> 3, k7 = kr & 7;
    int NC = K >> 6;
    for (int c = 0; c < NC; c++){
        __syncthreads();
        *(float4*)&As[da0] = a0p; *(float4*)&As[da1] = a1p;
        const ushort* bw0 = (const ushort*)&b0p;
        const ushort* bw1 = (const ushort*)&b1p;
        #pragma unroll
        for (int j = 0; j < 8; j++){
            int nn = ng*16 + j;
            Bs[nn*64 + ((kg^(nn&7))<<3) + k7] = bw0[j];
        }
        #pragma unroll
        for (int j = 0; j < 8; j++){
            int nn = ng*16 + 8 + j;
            Bs[nn*64 + ((kg^(nn&7))<<3) + k7] = bw1[j];
        }
        __syncthreads();
        if (c + 1 < NC){
            int k0 = (c+1)*64;
            a0p = *(const float4*)(Ab + baseA + (size_t)arow0*K + k0 + ag*8);
            a1p = *(const float4*)(Ab + baseA + (size_t)arow1*K + k0 + ag*8);
            b0p = *(const float4*)(Wb + (size_t)(k0+kr)*NH + cb*64 + ng*16);
            b1p = *(const float4*)(Wb + (size_t)(k0+kr)*NH + cb*64 + ng*16 + 8);
        }
        #pragma unroll
        for (int ks = 0; ks < 4; ks++){
            int gq = ks*2 + hi;
            v8s a = *(const v8s*)&As[ra0 + ((gq^fr7a)<<3)];
            v8s b = *(const v8s*)&Bs[rbp + ((gq^fr7b)<<3)];
            acc = __builtin_amdgcn_mfma_f32_32x32x16_bf16(a, b, acc, 0, 0, 0);
        }
    }
    int n  = cb*64 + wwc*32 + l31;
    int mb = rb*64 + wwr*32 + 4*hi;
    #pragma unroll
    for (int i = 0; i < 16; i++){
        int m = mb + (i&3) + 8*(i>>2);
        XW[(size_t)m*NH + n] = acc[i];
    }
}

// ---------------- Gram pass 1 (max/tmin) + fused layer-1 XW ----------------
template<int PASS>
__global__ __launch_bounds__(256) void k_gram(const ushort* __restrict__ Xb,
        const float* __restrict__ sq, unsigned* __restrict__ maxd2,
        float* __restrict__ tmin, unsigned* __restrict__ ecnt,
        unsigned* __restrict__ edges, float* __restrict__ deg,
        const ushort* __restrict__ Wb, float* __restrict__ XW){
    __shared__ __align__(16) ushort As[64*64];
    __shared__ __align__(16) ushort Bs[64*64];
    int b = blockIdx.x;
    if (PASS == 1){
        if (b < 256){
            xw_body(Xb, Wb, XW, b >> 2, b & 3, DIN, As, Bs);
            return;
        }
        b -= 256;
    }
    float ff = sqrtf(8.f*(float)b + 1.f);
    int rb = (int)((ff - 1.f) * 0.5f);
    while ((rb+1)*(rb+2)/2 <= b) rb++;
    while (rb*(rb+1)/2 > b) rb--;
    int cb = b - rb*(rb+1)/2;

    int tid = threadIdx.x;
    int lane = tid & 63, wv = tid >> 6;
    int l31 = lane & 31, hi = lane >> 5;
    int wwr = wv >> 1, wwc = wv & 1;
    v16f acc = mm_tile(Xb + (size_t)rb*64*DIN, Xb + (size_t)cb*64*DIN, DIN,
                       As, Bs, tid, wv, l31, hi);
    int rbase = rb*64 + wwr*32 + 4*hi;
    int col   = cb*64 + wwc*32 + l31;
    float sqc = sq[col];
    float m = 0.f, mn = INFINITY;
    #pragma unroll
    for (int i = 0; i < 16; i++){
        int r = rbase + (i&3) + 8*(i>>2);
        float d2 = sq[r] + sqc - 2.f*acc[i];
        if (r != col) m = fmaxf(m, d2);
        if (r > col)  mn = fminf(mn, d2);
    }
    #pragma unroll
    for (int off = 32; off >= 1; off >>= 1){
        m  = fmaxf(m,  __shfl_down(m,  off));
        mn = fminf(mn, __shfl_down(mn, off));
    }
    __shared__ float wmax[4], wmin[4];
    if (lane == 0){ wmax[wv] = m; wmin[wv] = mn; }
    __syncthreads();
    if (tid == 0){
        float mm = fmaxf(fmaxf(wmax[0], wmax[1]), fmaxf(wmax[2], wmax[3]));
        tmin[rb*64 + cb] = fminf(fminf(wmin[0], wmin[1]), fminf(wmin[2], wmin[3]));
        atomicMax(maxd2, __float_as_uint(fmaxf(mm, 0.f)));  // non-neg: uint order ok
    }
}

// ---- radix-scan (256 threads): thread t owns bins [t*G, t*G+G). -----------
static __device__ __forceinline__ uint2 rscan256(const uint* hist, uint* wcnt,
        uint* sh, int t, int lane, int wv, uint kk, int G){
    int b0 = t * G;
    uint loc = 0;
    for (int j = 0; j < G; j++) loc += hist[b0 + j];
    uint s = loc;
    #pragma unroll
    for (int off = 1; off < 64; off <<= 1){
        uint u = __shfl_down(s, off);
        if (lane + off < 64) s += u;
    }
    if (lane == 0) wcnt[wv] = s;
    __syncthreads();
    uint aw = 0;
    for (int w = wv + 1; w < 4; w++) aw += wcnt[w];
    uint run = aw + (s - loc);
    for (int bb = b0 + G - 1; bb >= b0; bb--){
        uint h = hist[bb];
        if (run < kk && run + h >= kk){ sh[0] = (uint)bb; sh[1] = run; }
        run += h;
    }
    __syncthreads();
    uint2 r; r.x = sh[0]; r.y = sh[1];
    __syncthreads();
    return r;
}

// ---------------- cooperative tail: gram2 + 3x(score|select|xwp) + pool ----
struct TailArgs {
    const ushort* Xb; const float* sq; const unsigned* maxd2; const float* tmin;
    unsigned* ecnt; unsigned* E0; unsigned* E1;
    float* degA; float* degB;
    float* Xn; float* XW; const ushort* Wb;
    float* s1; float* z; int* perm; float* svals; int* rnk;
    uint* maxU; float* sums; float* out;
    const void* bias[3]; const void* Wnp[3]; const void* Wrp[3]; const void* bsp[3];
    const unsigned* dflag;
};

__global__ __launch_bounds__(256, 4) void k_tail(TailArgs ta){
    cg::grid_group gg = cg::this_grid();
    __shared__ __align__(16) char SMEM[32768];
    __shared__ unsigned sEsh;
    __shared__ float sra[4], srbv[4];
    __shared__ uint swcnt[4], ssh[4];

    const int tid = threadIdx.x, lane = tid & 63, wv = tid >> 6;
    const int bid = blockIdx.x, nblk = gridDim.x;
    const int l31 = lane & 31, hi = lane >> 5;

    // ================= phase: gram pass 2 (edge extraction) =================
    {
        ushort* As = (ushort*)SMEM;
        ushort* Bs = (ushort*)(SMEM + 8192);
        float tthr = 0.5f * __uint_as_float(ta.maxd2[0]);
        for (int b = bid; b < NTRI; b += nblk){
            float ff = sqrtf(8.f*(float)b + 1.f);
            int rb = (int)((ff - 1.f) * 0.5f);
            while ((rb+1)*(rb+2)/2 <= b) rb++;
            while (rb*(rb+1)/2 > b) rb--;
            int cb = b - rb*(rb+1)/2;
            if (ta.tmin[rb*64 + cb] >= tthr) continue;   // block-uniform
            v16f acc = mm_tile(ta.Xb + (size_t)rb*64*DIN, ta.Xb + (size_t)cb*64*DIN,
                               DIN, As, Bs, tid, wv, l31, hi);
            int wwr = wv >> 1, wwc = wv & 1;
            int rbase = rb*64 + wwr*32 + 4*hi;
            int col   = cb*64 + wwc*32 + l31;
            float sqc = ta.sq[col];
            #pragma unroll
            for (int i = 0; i < 16; i++){
                int r = rbase + (i&3) + 8*(i>>2);
                float d2 = ta.sq[r] + sqc - 2.f*acc[i];
                if (r > col && d2 < tthr){
                    unsigned idx = atomicAdd(ta.ecnt, 1u);
                    if (idx < EDGE_CAP){
                        ta.E0[idx] = ((unsigned)r << 16) | (unsigned)col;
                        atomicAdd(&ta.degA[r], 1.0f);
                    }
                }
            }
        }
    }
    gg.sync();

    // ================= 3 layers =================
    #pragma unroll
    for (int L = 0; L < 3; L++){
        const int Nv   = (L==0) ? NN  : (L==1) ? KL1 : KL2;
        const int kv   = (L==0) ? KL1 : (L==1) ? KL2 : KL3;
        unsigned* eIn  = (L==1) ? ta.E1 : ta.E0;
        unsigned* eOut = (L==0) ? ta.E1 : (L==1) ? ta.E0 : nullptr;
        const int sIn  = L;
        const int sOut = (L < 2) ? L + 1 : -1;
        float* degp    = (L==1) ? ta.degB : ta.degA;
        float* degN    = (L==0) ? ta.degB : (L==1) ? ta.degA : nullptr;
        const int fb   = (L==0) ? 5  : (L==1) ? 7  : 9;
        const int fWn  = (L==0) ? 11 : (L==1) ? 14 : 17;
        const int fWr  = (L==0) ? 10 : (L==1) ? 13 : 16;
        const int fbs  = (L==0) ? 12 : (L==1) ? 15 : 18;

        // ---- score phase: aggregation + relu + scorer ----
        {
            unsigned* eL = (unsigned*)SMEM;
            if (tid == 0){
                unsigned E0v = ta.ecnt[sIn];
                sEsh = (E0v > EDGE_CAP) ? EDGE_CAP : E0v;
            }
            __syncthreads();
            unsigned E = sEsh;
            int fbv = (int)ta.dflag[fb], fWnv = (int)ta.dflag[fWn];
            int fWrv = (int)ta.dflag[fWr], fbsv = (int)ta.dflag[fbs];
            for (int row = bid; row < Nv; row += nblk){
                float disr = 1.0f / sqrtf(degp[row]);
                float acc = disr * ta.XW[(size_t)row*NH + tid];
                for (unsigned base = 0; base < E; base += 256){
                    unsigned nchunk = E - base; if (nchunk > 256) nchunk = 256;
                    __syncthreads();
                    if (tid < (int)nchunk) eL[tid] = eIn[base + tid];
                    __syncthreads();
                    for (unsigned j = 0; j < nchunk; j++){
                        unsigned ed = eL[j];
                        if ((int)(ed >> 16) == row){
                            int src = ed & 0xFFFFu;
                            acc += (1.0f / sqrtf(degp[src])) * ta.XW[(size_t)src*NH + tid];
                        }
                    }
                }
                float xn = fmaxf(fmaf(disr, acc, ldf(ta.bias[L], tid, fbv)), 0.f);
                ta.Xn[(size_t)row*NH + tid] = xn;
                float a  = xn * ldf(ta.Wnp[L], tid, fWnv);
                float bb = xn * ldf(ta.Wrp[L], tid, fWrv);
                #pragma unroll
                for (int off = 32; off >= 1; off >>= 1){
                    a += __shfl_down(a, off); bb += __shfl_down(bb, off);
                }
                if ((tid & 63) == 0){ sra[wv] = a; srbv[wv] = bb; }
                __syncthreads();
                if (tid == 0){
                    ta.s1[row] = sra[0]+sra[1]+sra[2]+sra[3];
                    ta.z[row]  = srbv[0]+srbv[1]+srbv[2]+srbv[3] + ldf(ta.bsp[L], 0, fbsv);
                }
                __syncthreads();   // protect sra/srbv reuse next row
            }
        }
        gg.sync();

        // ---- select phase (block 0 only; 256 threads) ----
        if (bid == 0){
            float* zsh = (float*)SMEM;            // 16 KB
            uint*  hist = (uint*)(SMEM + 16384);  // 16 KB
            int t = tid;
            for (int i = t; i < Nv; i += 256){ zsh[i] = ta.z[i]; ta.rnk[i] = -1; }
            if (degN) for (int i = t; i < kv; i += 256) degN[i] = 1.0f;
            if (t == 0) ssh[2] = 0u;
            __syncthreads();
            unsigned E = ta.ecnt[sIn]; if (E > EDGE_CAP) E = EDGE_CAP;
            for (unsigned e = t; e < E; e += 256){
                unsigned ed = eIn[e];
                atomicAdd(&zsh[ed >> 16], ta.s1[ed & 0xFFFFu]);
            }
            __syncthreads();
            uint c[16];
            #pragma unroll
            for (int j = 0; j < 16; j++){
                int i = t + j*256;
                c[j] = (i < Nv) ? fcode(zsh[i]) : 0u;
            }
            // pass 1: top 12 bits
            for (int i = t; i < 4096; i += 256) hist[i] = 0u;
            __syncthreads();
            #pragma unroll
            for (int j = 0; j < 16; j++)
                if (t + j*256 < Nv) atomicAdd(&hist[c[j] >> 20], 1u);
            __syncthreads();
            uint2 p1 = rscan256(hist, swcnt, ssh, t, lane, wv, (uint)kv, 16);
            uint B1 = p1.x; uint kk2 = (uint)kv - p1.y;
            // pass 2: middle 12 bits
            for (int i = t; i < 4096; i += 256) hist[i] = 0u;
            __syncthreads();
            #pragma unroll
            for (int j = 0; j < 16; j++)
                if (t + j*256 < Nv && (c[j] >> 20) == B1) atomicAdd(&hist[(c[j] >> 8) & 0xFFFu], 1u);
            __syncthreads();
            uint2 p2 = rscan256(hist, swcnt, ssh, t, lane, wv, kk2, 16);
            uint B2 = p2.x; uint kk3 = kk2 - p2.y;
            uint hi24 = (B1 << 12) | B2;
            // pass 3: low 8 bits
            for (int i = t; i < 256; i += 256) hist[i] = 0u;
            __syncthreads();
            #pragma unroll
            for (int j = 0; j < 16; j++)
                if (t + j*256 < Nv && (c[j] >> 8) == hi24) atomicAdd(&hist[c[j] & 0xFFu], 1u);
            __syncthreads();
            uint2 p3 = rscan256(hist, swcnt, ssh, t, lane, wv, kk3, 1);
            uint T = (B1 << 20) | (B2 << 8) | p3.x;

            // compaction: strict > ranked (deterministic), ties fill
            uint cnt = 0;
            #pragma unroll
            for (int j = 0; j < 16; j++)
                if (t + j*256 < Nv && c[j] > T) cnt++;
            uint inc = cnt;
            #pragma unroll
            for (int off = 1; off < 64; off <<= 1){
                uint u = __shfl_up(inc, off);
                if (lane >= off) inc += u;
            }
            if (lane == 63) swcnt[wv] = inc;
            __syncthreads();
            uint wb = 0;
            for (int w = 0; w < wv; w++) wb += swcnt[w];
            uint total = swcnt[0] + swcnt[1] + swcnt[2] + swcnt[3];
            uint r = wb + inc - cnt;
            #pragma unroll
            for (int j = 0; j < 16; j++){
                int i = t + j*256;
                if (i < Nv && c[j] > T){
                    ta.perm[r] = i; ta.svals[r] = tanhf(zsh[i]); ta.rnk[i] = (int)r; r++;
                }
            }
            uint cntGT = total, rem = (uint)kv - cntGT;
            #pragma unroll
            for (int j = 0; j < 16; j++){
                int i = t + j*256;
                if (i < Nv && c[j] == T){
                    uint e = atomicAdd(&ssh[2], 1u);
                    if (e < rem){
                        uint rr = cntGT + e;
                        ta.perm[rr] = i; ta.svals[rr] = tanhf(zsh[i]); ta.rnk[i] = (int)rr;
                    }
                }
            }
            __syncthreads();
            // edge filter to surviving nodes
            if (sOut >= 0){
                for (unsigned e = t; e < E; e += 256){
                    unsigned ed = eIn[e];
                    int nd = ta.rnk[ed >> 16], ns = ta.rnk[ed & 0xFFFFu];
                    if (nd >= 0 && ns >= 0){
                        unsigned idx = atomicAdd(&ta.ecnt[sOut], 1u);
                        if (idx < EDGE_CAP){
                            eOut[idx] = ((unsigned)nd << 16) | (unsigned)ns;
                            atomicAdd(&degN[nd], 1.0f);
                        }
                    }
                }
            }
        }
        gg.sync();

        // ---- xwp phase (layers 0,1): pool + X@W + prev-layer readout ----
        if (L < 2){
            ushort* As = (ushort*)SMEM;
            ushort* Bs = (ushort*)(SMEM + 8192);
            float* pmx = (float*)(SMEM + 16384);
            float* psm = (float*)(SMEM + 17408);
            const ushort* Wl = ta.Wb + ((L==0) ? 131072 : 196608);
            const int ntiles = (kv >> 6) * 4;
            int wwr = wv >> 1, wwc = wv & 1;
            int arow0 = tid >> 3, ag = tid & 7;
            int arow1 = arow0 + 32;
            int da0 = arow0*64 + ((ag^(arow0&7))<<3);
            int da1 = arow1*64 + ((ag^(arow1&7))<<3);
            int kr = tid >> 2, ng = tid & 3;
            int kg = kr >> 3, k7 = kr & 7;
            int ra0 = (wwr*32 + l31)*64, rbp = (wwc*32 + l31)*64;
            int fr7a = (wwr*32 + l31) & 7, fr7b = (wwc*32 + l31) & 7;
            for (int tile = bid; tile < ntiles; tile += nblk){
                int rb = tile >> 2, cb = tile & 3;
                int p0 = ta.perm[rb*64 + arow0]; float sv0 = ta.svals[rb*64 + arow0];
                int p1 = ta.perm[rb*64 + arow1]; float sv1 = ta.svals[rb*64 + arow1];
                float4 xa0 = *(const float4*)(ta.Xn + (size_t)p0*NH + ag*8);
                float4 xa1 = *(const float4*)(ta.Xn + (size_t)p0*NH + ag*8 + 4);
                float4 xb0 = *(const float4*)(ta.Xn + (size_t)p1*NH + ag*8);
                float4 xb1 = *(const float4*)(ta.Xn + (size_t)p1*NH + ag*8 + 4);
                float4 wb0 = *(const float4*)(Wl + (size_t)kr*NH + cb*64 + ng*16);
                float4 wb1 = *(const float4*)(Wl + (size_t)kr*NH + cb*64 + ng*16 + 8);
                v16f acc = {};
                for (int c = 0; c < 4; c++){
                    __syncthreads();
                    {
                        __align__(16) ushort tav[8];
                        tav[0]=f2b(xa0.x*sv0); tav[1]=f2b(xa0.y*sv0); tav[2]=f2b(xa0.z*sv0); tav[3]=f2b(xa0.w*sv0);
                        tav[4]=f2b(xa1.x*sv0); tav[5]=f2b(xa1.y*sv0); tav[6]=f2b(xa1.z*sv0); tav[7]=f2b(xa1.w*sv0);
                        *(float4*)&As[da0] = *(const float4*)tav;
                        __align__(16) ushort tbv[8];
                        tbv[0]=f2b(xb0.x*sv1); tbv[1]=f2b(xb0.y*sv1); tbv[2]=f2b(xb0.z*sv1); tbv[3]=f2b(xb0.w*sv1);
                        tbv[4]=f2b(xb1.x*sv1); tbv[5]=f2b(xb1.y*sv1); tbv[6]=f2b(xb1.z*sv1); tbv[7]=f2b(xb1.w*sv1);
                        *(float4*)&As[da1] = *(const float4*)tbv;
                    }
                    {
                        const ushort* bw0 = (const ushort*)&wb0;
                        const ushort* bw1 = (const ushort*)&wb1;
                        #pragma unroll
                        for (int j = 0; j < 8; j++){
                            int nn = ng*16 + j;
                            Bs[nn*64 + ((kg^(nn&7))<<3) + k7] = bw0[j];
                        }
                        #pragma unroll
                        for (int j = 0; j < 8; j++){
                            int nn = ng*16 + 8 + j;
                            Bs[nn*64 + ((kg^(nn&7))<<3) + k7] = bw1[j];
                        }
                    }
                    __syncthreads();
                    if (c < 3){
                        int k0 = (c+1)*64;
                        xa0 = *(const float4*)(ta.Xn + (size_t)p0*NH + k0 + ag*8);
                        xa1 = *(const float4*)(ta.Xn + (size_t)p0*NH + k0 + ag*8 + 4);
                        xb0 = *(const float4*)(ta.Xn + (size_t)p1*NH + k0 + ag*8);
                        xb1 = *(const float4*)(ta.Xn + (size_t)p1*NH + k0 + ag*8 + 4);
                        wb0 = *(const float4*)(Wl + (size_t)(k0+kr)*NH + cb*64 + ng*16);
                        wb1 = *(const float4*)(Wl + (size_t)(k0+kr)*NH + cb*64 + ng*16 + 8);
                    }
                    if (cb == 0){
                        int cc = tid & 63, q = tid >> 6;
                        int ggc = cc >> 3, c7 = cc & 7;
                        float m = -INFINITY, s = 0.f;
                        #pragma unroll
                        for (int i = 0; i < 16; i++){
                            int rr = q*16 + i;
                            float v = __uint_as_float(((uint)As[rr*64 + ((ggc^(rr&7))<<3) + c7]) << 16);
                            m = fmaxf(m, v); s += v;
                        }
                        pmx[tid] = m; psm[tid] = s;
                        __syncthreads();
                        if (tid < 64){
                            float mm = fmaxf(fmaxf(pmx[tid], pmx[tid+64]), fmaxf(pmx[tid+128], pmx[tid+192]));
                            float ss = psm[tid] + psm[tid+64] + psm[tid+128] + psm[tid+192];
                            atomicMax(&ta.maxU[L*NH + c*64 + tid], fcode(mm));
                            atomicAdd(&ta.sums[L*NH + c*64 + tid], ss);
                        }
                    }
                    #pragma unroll
                    for (int ks = 0; ks < 4; ks++){
                        int gq = ks*2 + hi;
                        v8s av = *(const v8s*)&As[ra0 + ((gq^fr7a)<<3)];
                        v8s bv = *(const v8s*)&Bs[rbp + ((gq^fr7b)<<3)];
                        acc = __builtin_amdgcn_mfma_f32_32x32x16_bf16(av, bv, acc, 0, 0, 0);
                    }
                }
                int n  = cb*64 + wwc*32 + l31;
                int mb = rb*64 + wwr*32 + 4*hi;
                #pragma unroll
                for (int i = 0; i < 16; i++){
                    int m = mb + (i&3) + 8*(i>>2);
                    ta.XW[(size_t)m*NH + n] = acc[i];
                }
            }
            gg.sync();
        }
    }

    // ================= pool phase: layer-3 readout partials =================
    if (bid < 64){
        float m = -INFINITY, s = 0.f;
        for (int r = bid; r < KL3; r += 64){
            int p = ta.perm[r];
            float v = ta.Xn[(size_t)p*NH + tid] * ta.svals[r];
            m = fmaxf(m, v); s += v;
        }
        atomicMax(&ta.maxU[2*NH + tid], fcode(m));
        atomicAdd(&ta.sums[2*NH + tid], s);
    }
    gg.sync();
    if (bid == 0){
        ta.out[tid] = fdecode(ta.maxU[tid]) + fdecode(ta.maxU[NH + tid])
                    + fdecode(ta.maxU[2*NH + tid]);
        ta.out[NH + tid] = ta.sums[tid]*(1.0f/KL1) + ta.sums[NH + tid]*(1.0f/KL2)
                         + ta.sums[2*NH + tid]*(1.0f/KL3);
    }
}

// =======================================================================
extern "C" void kernel_launch(void* const* d_in, const int* in_sizes, int n_in,
                              void* d_out, int out_size, void* d_ws, size_t ws_size,
                              hipStream_t stream)
{
    const void* b1 = d_in[5];
    const void* b2 = d_in[7];
    const void* b3 = d_in[9];
    const void* Wr1 = d_in[10]; const void* Wn1 = d_in[11]; const void* bs1 = d_in[12];
    const void* Wr2 = d_in[13]; const void* Wn2 = d_in[14]; const void* bs2 = d_in[15];
    const void* Wr3 = d_in[16]; const void* Wn3 = d_in[17]; const void* bs3 = d_in[18];

    char* w = (char*)d_ws;
    auto alloc = [&](size_t bytes)->char*{ char* p = w; w += (bytes + 255) & ~(size_t)255; return p; };
    ushort*   Xb    = (ushort*)  alloc((size_t)NN*DIN*2);
    float*    Xn    = (float*)   alloc((size_t)NN*NH*4);
    float*    XW    = (float*)   alloc((size_t)NN*NH*4);
    ushort*   Wb    = (ushort*)  alloc((size_t)262144*2);
    unsigned* E0    = (unsigned*)alloc((size_t)EDGE_CAP*4);
    unsigned* E1    = (unsigned*)alloc((size_t)EDGE_CAP*4);
    float*    tmin  = (float*)   alloc(4096*4);
    float*    sq    = (float*)   alloc(NN*4);
    float*    degA  = (float*)   alloc(NN*4);
    float*    degB  = (float*)   alloc(NN*4);
    float*    s1    = (float*)   alloc(NN*4);
    float*    z     = (float*)   alloc(NN*4);
    int*      perm  = (int*)     alloc(NN*4);
    float*    svals = (float*)   alloc(NN*4);
    int*      rnk   = (int*)     alloc(NN*4);
    unsigned* ecnt  = (unsigned*)alloc(256);
    unsigned* maxd2 = (unsigned*)alloc(256);
    unsigned* dflag = (unsigned*)alloc(256);
    uint*     maxU  = (uint*)    alloc(768*4);
    float*    sums  = (float*)   alloc(768*4);
    (void)ws_size;

    DtIn da;
    for (int i = 0; i < 19; i++){ da.p[i] = d_in[i]; da.n[i] = in_sizes[i]; }

    k_prep<<<NN + 65, 512, 0, stream>>>(da, Xb, sq, Wb, dflag, degA, maxU, sums,
            ecnt, maxd2, tmin);
    // gram pass 1: 256 fused XW tiles + 2080 triangle tiles (64x64, 1D grid)
    k_gram<1><<<256 + NTRI, 256, 0, stream>>>(Xb, sq, maxd2, tmin, ecnt, E0, degA,
            Wb, XW);

    // cooperative tail: gram2 + 3x(score|select|xwp) + pool + writeout
    TailArgs ta;
    ta.Xb = Xb; ta.sq = sq; ta.maxd2 = maxd2; ta.tmin = tmin;
    ta.ecnt = ecnt; ta.E0 = E0; ta.E1 = E1;
    ta.degA = degA; ta.degB = degB;
    ta.Xn = Xn; ta.XW = XW; ta.Wb = Wb;
    ta.s1 = s1; ta.z = z; ta.perm = perm; ta.svals = svals; ta.rnk = rnk;
    ta.maxU = maxU; ta.sums = sums; ta.out = (float*)d_out;
    ta.bias[0] = b1;  ta.bias[1] = b2;  ta.bias[2] = b3;
    ta.Wnp[0]  = Wn1; ta.Wnp[1]  = Wn2; ta.Wnp[2]  = Wn3;
    ta.Wrp[0]  = Wr1; ta.Wrp[1]  = Wr2; ta.Wrp[2]  = Wr3;
    ta.bsp[0]  = bs1; ta.bsp[1]  = bs2; ta.bsp[2]  = bs3;
    ta.dflag = dflag;

    int nb = 0;
    hipOccupancyMaxActiveBlocksPerMultiprocessor(&nb, k_tail, 256, 0);
    int grid = nb * 256;
    if (grid > 1024) grid = 1024;
    if (grid < 256)  grid = 256;
    void* kargs[] = { (void*)&ta };
    hipLaunchCooperativeKernel(k_tail, dim3(grid), dim3(256), kargs, 0u, stream);
}

// Round 8
// 231.490 us; speedup vs baseline: 3.3773x; 3.3773x over previous
//
#include <hip/hip_runtime.h>
#include <hip/hip_bf16.h>
#include <math.h>

typedef __hip_bfloat16 bf16;
typedef unsigned short ushort;
typedef unsigned int uint;
typedef unsigned long long ull;
static __device__ __forceinline__ float b2f(bf16 x){ return __bfloat162float(x); }

static __device__ __forceinline__ float ldf(const void* p, int i, int isbf){
    return isbf ? b2f(((const bf16*)p)[i]) : ((const float*)p)[i];
}
static __device__ __forceinline__ ushort f2b(float x){
    return __bfloat16_as_ushort(__float2bfloat16(x));
}
static __device__ __forceinline__ uint fcode(float v){
    uint u = __float_as_uint(v);
    return (u & 0x80000000u) ? ~u : (u | 0x80000000u);
}
static __device__ __forceinline__ float fdecode(uint c){
    uint u = (c & 0x80000000u) ? (c & 0x7FFFFFFFu) : ~c;
    return __uint_as_float(u);
}

#define NN    4096
#define FEAT0 500
#define DIN   512
#define NH    256
#define KL1   3072
#define KL2   2304
#define KL3   1728
#define EDGE_CAP 786432u
#define NTRI  2080   // 64*65/2 lower-triangle tiles at 64x64

typedef __attribute__((ext_vector_type(8)))  short v8s;
typedef __attribute__((ext_vector_type(16))) float v16f;

// async global->LDS, 16B/lane. LDS dest is wave-uniform base + lane*16;
// global src is per-lane (pre-swizzled to preserve the XOR LDS layout).
static __device__ __forceinline__ void gl_lds16(const ushort* g, ushort* l){
    __builtin_amdgcn_global_load_lds(
        (const __attribute__((address_space(1))) void*)g,
        (__attribute__((address_space(3))) void*)l, 16, 0, 0);
}

// check min(n,256) leading 16-bit halves; bf16 data here has |v|<64 (exp<135);
// fp32 misread has uniform-random exponent fields.
static __device__ __forceinline__ void detect_bf16(const void* p, int n, int t,
        uint* flag){
    if (t < 256 && t < n){
        uint e = ((uint)((const ushort*)p)[t] >> 7) & 0xFFu;
        if (e >= 135u) atomicAnd(flag, 0u);
    }
}

// ---------------- prep: pos MLP + concat + W-convert + ALL inits -----------
// blocks [0,NN): rows; [NN,NN+64): W1|W2|W3 -> bf16; block NN+64: inits+dflag
struct DtIn { const void* p[19]; int n[19]; };
__global__ __launch_bounds__(512) void k_prep(DtIn da,
        ushort* __restrict__ Xb, float* __restrict__ sq, ushort* __restrict__ Wb,
        unsigned* __restrict__ dflag, float* __restrict__ degA,
        uint* __restrict__ maxU, float* __restrict__ sums,
        unsigned* __restrict__ ecnt, unsigned* __restrict__ maxd2,
        float* __restrict__ tmin){
    int row = blockIdx.x, t = threadIdx.x;
    if (row < NN){
        __shared__ uint fl[4];
        if (t < 4) fl[t] = 1u;
        __syncthreads();
        detect_bf16(da.p[0], da.n[0], t, &fl[0]);   // feature
        detect_bf16(da.p[1], da.n[1], t, &fl[1]);   // img
        detect_bf16(da.p[2], da.n[2], t, &fl[2]);   // Wpos
        detect_bf16(da.p[3], da.n[3], t, &fl[3]);   // bpos
        __syncthreads();
        int f_feat = (int)fl[0], f_img = (int)fl[1], f_wp = (int)fl[2], f_bp = (int)fl[3];
        float v;
        if (t < FEAT0) v = ldf(da.p[0], row*FEAT0 + t, f_feat);
        else {
            int c = t - FEAT0;
            float acc = ldf(da.p[3], c, f_bp);
            #pragma unroll
            for (int d = 0; d < 6; d++)
                acc += ldf(da.p[1], row*6+d, f_img) * ldf(da.p[2], d*12+c, f_wp);
            v = fmaxf(acc, 0.f);
        }
        bf16 vb = __float2bfloat16(v);
        Xb[row*DIN + t] = __bfloat16_as_ushort(vb);
        float vr = b2f(vb);                 // sq of rounded vector -> d2 exact
        float vsq = vr*vr;
        #pragma unroll
        for (int off = 32; off >= 1; off >>= 1) vsq += __shfl_down(vsq, off);
        __shared__ float red[8];
        if ((t & 63) == 0) red[t >> 6] = vsq;
        __syncthreads();
        if (t == 0){
            float sres = 0.f;
            #pragma unroll
            for (int i = 0; i < 8; i++) sres += red[i];
            sq[row] = sres;
        }
    } else if (row < NN + 64){
        __shared__ uint fl[3];
        if (t < 3) fl[t] = 1u;
        __syncthreads();
        detect_bf16(da.p[4], da.n[4], t, &fl[0]);   // W1
        detect_bf16(da.p[6], da.n[6], t, &fl[1]);   // W2
        detect_bf16(da.p[8], da.n[8], t, &fl[2]);   // W3
        __syncthreads();
        int i0 = ((row - NN)*512 + t)*8;
        #pragma unroll
        for (int j = 0; j < 8; j++){
            int idx = i0 + j;
            float v;
            if (idx < 131072)       v = ldf(da.p[4], idx,          (int)fl[0]);
            else if (idx < 196608)  v = ldf(da.p[6], idx - 131072, (int)fl[1]);
            else                    v = ldf(da.p[8], idx - 196608, (int)fl[2]);
            Wb[idx] = __bfloat16_as_ushort(__float2bfloat16(v));
        }
    } else {
        // inits + PARALLEL dflag scan (was: 19 threads x serial 256-load loop,
        // a ~25-40us latency chain gating the whole dispatch; now one parallel
        // burst over all 512 threads -- identical positions checked).
        __shared__ uint fl19[19];
        if (t < 19) fl19[t] = 1u;
        for (int i = t; i < NN; i += 512) degA[i] = 1.0f;
        for (int i = t; i < 4096; i += 512) tmin[i] = INFINITY;
        for (int i = t; i < 768; i += 512){ maxU[i] = 0x007FFFFFu; sums[i] = 0.f; }
        if (t == 0){
            #pragma unroll
            for (int i = 0; i < 8; i++) ecnt[i] = 0u;
            maxd2[0] = 0u;
        }
        __syncthreads();
        for (int idx = t; idx < 19*256; idx += 512){
            int i = idx >> 8, j = idx & 255;
            if (j < da.n[i]){
                uint e = ((uint)((const ushort*)da.p[i])[j] >> 7) & 0xFFu;
                if (e >= 135u) atomicAnd(&fl19[i], 0u);
            }
        }
        __syncthreads();
        if (t < 19) dflag[t] = fl19[t];
    }
}

// 64x64 MFMA tile of A·B^T from row-major bf16, K cols (gl_lds staging).
static __device__ __forceinline__ v16f mm_tile(const ushort* __restrict__ Arows,
        const ushort* __restrict__ Brows, int K, ushort* As, ushort* Bs,
        int tid, int wv, int l31, int hi){
    int lane = tid & 63;
    int ro = lane >> 3, cch = lane & 7;
    int r0 = wv*16 + ro, r1 = wv*16 + 8 + ro;
    const ushort* gA0 = Arows + (size_t)r0*K + ((cch ^ (r0&7))<<3);
    const ushort* gA1 = Arows + (size_t)r1*K + ((cch ^ (r1&7))<<3);
    const ushort* gB0 = Brows + (size_t)r0*K + ((cch ^ (r0&7))<<3);
    const ushort* gB1 = Brows + (size_t)r1*K + ((cch ^ (r1&7))<<3);
    ushort* lA0 = As + (wv*16)*64;
    ushort* lA1 = As + (wv*16+8)*64;
    ushort* lB0 = Bs + (wv*16)*64;
    ushort* lB1 = Bs + (wv*16+8)*64;
    int wwr = wv >> 1, wwc = wv & 1;
    int ra0 = (wwr*32 + l31)*64, rbp = (wwc*32 + l31)*64;
    int fr7a = (wwr*32 + l31) & 7, fr7b = (wwc*32 + l31) & 7;
    v16f acc = {};
    int NC = K >> 6;
    for (int c = 0; c < NC; c++){
        int k0 = c*64;
        __syncthreads();
        gl_lds16(gA0 + k0, lA0);
        gl_lds16(gA1 + k0, lA1);
        gl_lds16(gB0 + k0, lB0);
        gl_lds16(gB1 + k0, lB1);
        __syncthreads();
        #pragma unroll
        for (int ks = 0; ks < 4; ks++){
            int gq = ks*2 + hi;
            v8s a = *(const v8s*)&As[ra0 + ((gq^fr7a)<<3)];
            v8s b = *(const v8s*)&Bs[rbp + ((gq^fr7b)<<3)];
            acc = __builtin_amdgcn_mfma_f32_32x32x16_bf16(a, b, acc, 0, 0, 0);
        }
    }
    return acc;
}

// ---------------- X @ W via MFMA (bf16 input), 64x64 tile ------------------
static __device__ __forceinline__ void xw_body(const ushort* __restrict__ Ab,
        const ushort* __restrict__ Wb, float* __restrict__ XW, int rb, int cb,
        int K, ushort* As, ushort* Bs){
    int tid = threadIdx.x, lane = tid & 63, wv = tid >> 6;
    int wwr = wv >> 1, wwc = wv & 1;
    int l31 = lane & 31, hi = lane >> 5;
    int arow0 = tid >> 3, ag = tid & 7;
    int arow1 = arow0 + 32;
    int da0 = arow0*64 + ((ag^(arow0&7))<<3);
    int da1 = arow1*64 + ((ag^(arow1&7))<<3);
    const size_t baseA = (size_t)rb*64*K;
    int kr = tid >> 2, ng = tid & 3;
    float4 a0p = *(const float4*)(Ab + baseA + (size_t)arow0*K + ag*8);
    float4 a1p = *(const float4*)(Ab + baseA + (size_t)arow1*K + ag*8);
    float4 b0p = *(const float4*)(Wb + (size_t)kr*NH + cb*64 + ng*16);
    float4 b1p = *(const float4*)(Wb + (size_t)kr*NH + cb*64 + ng*16 + 8);
    v16f acc = {};
    int ra0 = (wwr*32 + l31)*64, rbp = (wwc*32 + l31)*64;
    int fr7a = (wwr*32 + l31) & 7, fr7b = (wwc*32 + l31) & 7;
    int kg = kr >> 3, k7 = kr & 7;
    int NC = K >> 6;
    for (int c = 0; c < NC; c++){
        __syncthreads();
        *(float4*)&As[da0] = a0p; *(float4*)&As[da1] = a1p;
        const ushort* bw0 = (const ushort*)&b0p;
        const ushort* bw1 = (const ushort*)&b1p;
        #pragma unroll
        for (int j = 0; j < 8; j++){
            int nn = ng*16 + j;
            Bs[nn*64 + ((kg^(nn&7))<<3) + k7] = bw0[j];
        }
        #pragma unroll
        for (int j = 0; j < 8; j++){
            int nn = ng*16 + 8 + j;
            Bs[nn*64 + ((kg^(nn&7))<<3) + k7] = bw1[j];
        }
        __syncthreads();
        if (c + 1 < NC){
            int k0 = (c+1)*64;
            a0p = *(const float4*)(Ab + baseA + (size_t)arow0*K + k0 + ag*8);
            a1p = *(const float4*)(Ab + baseA + (size_t)arow1*K + k0 + ag*8);
            b0p = *(const float4*)(Wb + (size_t)(k0+kr)*NH + cb*64 + ng*16);
            b1p = *(const float4*)(Wb + (size_t)(k0+kr)*NH + cb*64 + ng*16 + 8);
        }
        #pragma unroll
        for (int ks = 0; ks < 4; ks++){
            int gq = ks*2 + hi;
            v8s a = *(const v8s*)&As[ra0 + ((gq^fr7a)<<3)];
            v8s b = *(const v8s*)&Bs[rbp + ((gq^fr7b)<<3)];
            acc = __builtin_amdgcn_mfma_f32_32x32x16_bf16(a, b, acc, 0, 0, 0);
        }
    }
    int n  = cb*64 + wwc*32 + l31;
    int mb = rb*64 + wwr*32 + 4*hi;
    #pragma unroll
    for (int i = 0; i < 16; i++){
        int m = mb + (i&3) + 8*(i>>2);
        XW[(size_t)m*NH + n] = acc[i];
    }
}

// ---------------- Gram via MFMA, 64x64 tile, triangular 1D grid ------------
// PASS 1: blocks [0,256) = fused layer-1 XW tiles; [256, 256+NTRI) = triangle
// PASS 2: blocks [0,NTRI) = triangle
template<int PASS>
__global__ __launch_bounds__(256) void k_gram(const ushort* __restrict__ Xb,
        const float* __restrict__ sq, unsigned* __restrict__ maxd2,
        float* __restrict__ tmin, unsigned* __restrict__ ecnt,
        unsigned* __restrict__ edges, float* __restrict__ deg,
        const ushort* __restrict__ Wb, float* __restrict__ XW){
    __shared__ __align__(16) ushort As[64*64];
    __shared__ __align__(16) ushort Bs[64*64];
    int b = blockIdx.x;
    if (PASS == 1){
        if (b < 256){
            xw_body(Xb, Wb, XW, b >> 2, b & 3, DIN, As, Bs);
            return;
        }
        b -= 256;
    }
    // triangular decode: b -> (rb, cb), cb <= rb
    float ff = sqrtf(8.f*(float)b + 1.f);
    int rb = (int)((ff - 1.f) * 0.5f);
    while ((rb+1)*(rb+2)/2 <= b) rb++;
    while (rb*(rb+1)/2 > b) rb--;
    int cb = b - rb*(rb+1)/2;

    int tid = threadIdx.x;
    float tthr = 0.f;
    if (PASS == 2){
        tthr = 0.5f * __uint_as_float(maxd2[0]);
        if (tmin[rb*64 + cb] >= tthr) return;   // block-uniform skip (exact bound)
    }
    int lane = tid & 63, wv = tid >> 6;
    int l31 = lane & 31, hi = lane >> 5;
    int wwr = wv >> 1, wwc = wv & 1;
    v16f acc = mm_tile(Xb + (size_t)rb*64*DIN, Xb + (size_t)cb*64*DIN, DIN,
                       As, Bs, tid, wv, l31, hi);
    int rbase = rb*64 + wwr*32 + 4*hi;
    int col   = cb*64 + wwc*32 + l31;
    float sqc = sq[col];
    if (PASS == 1){
        float m = 0.f, mn = INFINITY;
        #pragma unroll
        for (int i = 0; i < 16; i++){
            int r = rbase + (i&3) + 8*(i>>2);
            float d2 = sq[r] + sqc - 2.f*acc[i];
            if (r != col) m = fmaxf(m, d2);
            if (r > col)  mn = fminf(mn, d2);
        }
        #pragma unroll
        for (int off = 32; off >= 1; off >>= 1){
            m  = fmaxf(m,  __shfl_down(m,  off));
            mn = fminf(mn, __shfl_down(mn, off));
        }
        __shared__ float wmax[4], wmin[4];
        if (lane == 0){ wmax[wv] = m; wmin[wv] = mn; }
        __syncthreads();
        if (tid == 0){
            float mm = fmaxf(fmaxf(wmax[0], wmax[1]), fmaxf(wmax[2], wmax[3]));
            tmin[rb*64 + cb] = fminf(fminf(wmin[0], wmin[1]), fminf(wmin[2], wmin[3]));
            atomicMax(maxd2, __float_as_uint(fmaxf(mm, 0.f)));  // non-neg: uint order ok
        }
    } else {
        #pragma unroll
        for (int i = 0; i < 16; i++){
            int r = rbase + (i&3) + 8*(i>>2);
            float d2 = sq[r] + sqc - 2.f*acc[i];
            if (r > col && d2 < tthr){
                unsigned idx = atomicAdd(ecnt, 1u);
                if (idx < EDGE_CAP){
                    edges[idx] = ((unsigned)r << 16) | (unsigned)col;  // dst<<16|src
                    atomicAdd(&deg[r], 1.0f);
                }
            }
        }
    }
}

// ---------------- fused pool + X@W + prev-layer readout (layers 2,3) -------
__global__ __launch_bounds__(256) void k_xwp(const float* __restrict__ Xn,
        const int* __restrict__ perm, const float* __restrict__ svals,
        const ushort* __restrict__ Wb, float* __restrict__ XW, int M,
        uint* __restrict__ maxU, float* __restrict__ sums, int layer){
    int rb = blockIdx.x, cb = blockIdx.y;     // grid (M/64, 4); K = NH = 256
    __shared__ __align__(16) ushort As[64*64];
    __shared__ __align__(16) ushort Bs[64*64];
    __shared__ float pmx[256], psm[256];
    int tid = threadIdx.x, lane = tid & 63, wv = tid >> 6;
    int wwr = wv >> 1, wwc = wv & 1;
    int l31 = lane & 31, hi = lane >> 5;
    int arow0 = tid >> 3, ag = tid & 7;
    int arow1 = arow0 + 32;
    int da0 = arow0*64 + ((ag^(arow0&7))<<3);
    int da1 = arow1*64 + ((ag^(arow1&7))<<3);
    int p0 = perm[rb*64 + arow0]; float sv0 = svals[rb*64 + arow0];
    int p1 = perm[rb*64 + arow1]; float sv1 = svals[rb*64 + arow1];
    int kr = tid >> 2, ng = tid & 3;
    int kg = kr >> 3, k7 = kr & 7;
    int ra0 = (wwr*32 + l31)*64, rbp = (wwc*32 + l31)*64;
    int fr7a = (wwr*32 + l31) & 7, fr7b = (wwc*32 + l31) & 7;

    float4 xa0 = *(const float4*)(Xn + (size_t)p0*NH + ag*8);
    float4 xa1 = *(const float4*)(Xn + (size_t)p0*NH + ag*8 + 4);
    float4 xb0 = *(const float4*)(Xn + (size_t)p1*NH + ag*8);
    float4 xb1 = *(const float4*)(Xn + (size_t)p1*NH + ag*8 + 4);
    float4 wb0 = *(const float4*)(Wb + (size_t)kr*NH + cb*64 + ng*16);
    float4 wb1 = *(const float4*)(Wb + (size_t)kr*NH + cb*64 + ng*16 + 8);

    v16f acc = {};
    for (int c = 0; c < 4; c++){
        __syncthreads();
        {
            __align__(16) ushort ta[8];
            ta[0]=f2b(xa0.x*sv0); ta[1]=f2b(xa0.y*sv0); ta[2]=f2b(xa0.z*sv0); ta[3]=f2b(xa0.w*sv0);
            ta[4]=f2b(xa1.x*sv0); ta[5]=f2b(xa1.y*sv0); ta[6]=f2b(xa1.z*sv0); ta[7]=f2b(xa1.w*sv0);
            *(float4*)&As[da0] = *(const float4*)ta;
            __align__(16) ushort tb[8];
            tb[0]=f2b(xb0.x*sv1); tb[1]=f2b(xb0.y*sv1); tb[2]=f2b(xb0.z*sv1); tb[3]=f2b(xb0.w*sv1);
            tb[4]=f2b(xb1.x*sv1); tb[5]=f2b(xb1.y*sv1); tb[6]=f2b(xb1.z*sv1); tb[7]=f2b(xb1.w*sv1);
            *(float4*)&As[da1] = *(const float4*)tb;
        }
        {
            const ushort* bw0 = (const ushort*)&wb0;
            const ushort* bw1 = (const ushort*)&wb1;
            #pragma unroll
            for (int j = 0; j < 8; j++){
                int nn = ng*16 + j;
                Bs[nn*64 + ((kg^(nn&7))<<3) + k7] = bw0[j];
            }
            #pragma unroll
            for (int j = 0; j < 8; j++){
                int nn = ng*16 + 8 + j;
                Bs[nn*64 + ((kg^(nn&7))<<3) + k7] = bw1[j];
            }
        }
        __syncthreads();
        if (c < 3){
            int k0 = (c+1)*64;
            xa0 = *(const float4*)(Xn + (size_t)p0*NH + k0 + ag*8);
            xa1 = *(const float4*)(Xn + (size_t)p0*NH + k0 + ag*8 + 4);
            xb0 = *(const float4*)(Xn + (size_t)p1*NH + k0 + ag*8);
            xb1 = *(const float4*)(Xn + (size_t)p1*NH + k0 + ag*8 + 4);
            wb0 = *(const float4*)(Wb + (size_t)(k0+kr)*NH + cb*64 + ng*16);
            wb1 = *(const float4*)(Wb + (size_t)(k0+kr)*NH + cb*64 + ng*16 + 8);
        }
        if (cb == 0){
            int cc = tid & 63, q = tid >> 6;
            int gg = cc >> 3, c7 = cc & 7;
            float m = -INFINITY, s = 0.f;
            #pragma unroll
            for (int i = 0; i < 16; i++){
                int rr = q*16 + i;
                float v = __uint_as_float(((uint)As[rr*64 + ((gg^(rr&7))<<3) + c7]) << 16);
                m = fmaxf(m, v); s += v;
            }
            pmx[tid] = m; psm[tid] = s;
            __syncthreads();
            if (tid < 64){
                float mm = fmaxf(fmaxf(pmx[tid], pmx[tid+64]), fmaxf(pmx[tid+128], pmx[tid+192]));
                float ss = psm[tid] + psm[tid+64] + psm[tid+128] + psm[tid+192];
                atomicMax(&maxU[layer*NH + c*64 + tid], fcode(mm));
                atomicAdd(&sums[layer*NH + c*64 + tid], ss);
            }
        }
        #pragma unroll
        for (int ks = 0; ks < 4; ks++){
            int gq = ks*2 + hi;
            v8s a = *(const v8s*)&As[ra0 + ((gq^fr7a)<<3)];
            v8s b = *(const v8s*)&Bs[rbp + ((gq^fr7b)<<3)];
            acc = __builtin_amdgcn_mfma_f32_32x32x16_bf16(a, b, acc, 0, 0, 0);
        }
    }
    int n  = cb*64 + wwc*32 + l31;
    int mb = rb*64 + wwr*32 + 4*hi;
    #pragma unroll
    for (int i = 0; i < 16; i++){
        int m = mb + (i&3) + 8*(i>>2);
        XW[(size_t)m*NH + n] = acc[i];
    }
}

// ---- fused GCN finish: edge-scan aggregation + relu + scorer --------------
__global__ __launch_bounds__(256) void k_gcnscore(const float* __restrict__ XW,
        const unsigned* __restrict__ edges, const unsigned* __restrict__ ecnt, int slot,
        const float* __restrict__ deg, const void* __restrict__ b,
        const void* __restrict__ Wn, const void* __restrict__ Wr, const void* __restrict__ bs,
        const unsigned* __restrict__ fb, const unsigned* __restrict__ fWn,
        const unsigned* __restrict__ fWr, const unsigned* __restrict__ fbs,
        float* __restrict__ Xn, float* __restrict__ s1, float* __restrict__ z){
    int row = blockIdx.x, t = threadIdx.x;
    __shared__ unsigned eL[256];
    __shared__ unsigned Esh;
    if (t == 0){ unsigned E0 = ecnt[slot]; Esh = (E0 > EDGE_CAP) ? EDGE_CAP : E0; }
    __syncthreads();
    unsigned E = Esh;
    float disr = 1.0f / sqrtf(deg[row]);
    float acc = disr * XW[row*NH + t];
    for (unsigned base = 0; base < E; base += 256){
        unsigned nchunk = E - base; if (nchunk > 256) nchunk = 256;
        __syncthreads();
        if (t < nchunk) eL[t] = edges[base + t];
        __syncthreads();
        for (unsigned j = 0; j < nchunk; j++){
            unsigned ed = eL[j];
            if ((int)(ed >> 16) == row){
                int src = ed & 0xFFFFu;
                acc += (1.0f / sqrtf(deg[src])) * XW[src*NH + t];
            }
        }
    }
    float xn = fmaxf(fmaf(disr, acc, ldf(b, t, (int)fb[0])), 0.f);
    Xn[row*NH + t] = xn;
    float a  = xn * ldf(Wn, t, (int)fWn[0]);
    float bb = xn * ldf(Wr, t, (int)fWr[0]);
    for (int off = 32; off >= 1; off >>= 1){ a += __shfl_down(a, off); bb += __shfl_down(bb, off); }
    __shared__ float ra[4], rbv[4];
    int w = t >> 6;
    if ((t & 63) == 0){ ra[w] = a; rbv[w] = bb; }
    __syncthreads();
    if (t == 0){
        s1[row] = ra[0]+ra[1]+ra[2]+ra[3];
        z[row]  = rbv[0]+rbv[1]+rbv[2]+rbv[3] + ldf(bs, 0, (int)fbs[0]);
    }
}

// ---- radix-select helper: suffix-scan a shared histogram, find the bucket
// containing the kk-th largest element. Returns (bucket, count strictly above).
static __device__ __forceinline__ uint2 radix_scan(const uint* hist, uint* wt,
        uint* ws, uint* sh, int t, int lane, int wv, uint kk, int NB){
    uint loc = 0;
    int b0 = t << 2;
    if (b0 < NB) loc = hist[b0] + hist[b0+1] + hist[b0+2] + hist[b0+3];
    uint s = loc;
    #pragma unroll
    for (int off = 1; off < 64; off <<= 1){
        uint u = __shfl_down(s, off);
        if (lane + off < 64) s += u;
    }
    if (lane == 0) wt[wv] = s;               // wave total (inclusive suffix @lane0)
    __syncthreads();
    if (t < 16){
        uint a = 0;
        for (int j = t + 1; j < 16; j++) a += wt[j];
        ws[t] = a;                           // count in waves above
    }
    __syncthreads();
    if (b0 < NB){
        uint run = ws[wv] + (s - loc);       // count in bins strictly above my group
        for (int b = b0 + 3; b >= b0; b--){
            uint h = hist[b];
            if (run < kk && run + h >= kk){ sh[0] = (uint)b; sh[1] = run; }
            run += h;
        }
    }
    __syncthreads();
    return make_uint2(sh[0], sh[1]);
}

// ---------------- fused: scoredge + radix top-k select + efilter -----------
__global__ __launch_bounds__(1024) void k_select(const float* __restrict__ z,
        const float* __restrict__ s1, int N, int k,
        const unsigned* __restrict__ eIn, unsigned* __restrict__ ecnt, int slotCur,
        unsigned* __restrict__ eOut, int slotOut,
        int* __restrict__ perm, float* __restrict__ svals,
        float* __restrict__ degN, int Nnext){
    __shared__ float zsh[4096];
    __shared__ int   rnk[4096];
    __shared__ uint  hist[4096];
    __shared__ uint  wcnt[16];
    __shared__ uint  wbase[16];
    __shared__ uint  sh[4];
    int t = threadIdx.x;
    int lane = t & 63, wv = t >> 6;
    for (int i = t; i < N; i += 1024){ zsh[i] = z[i]; rnk[i] = -1; }
    for (int i = t; i < Nnext; i += 1024) degN[i] = 1.0f;
    if (t == 0) sh[2] = 0u;
    __syncthreads();
    unsigned E = ecnt[slotCur]; if (E > EDGE_CAP) E = EDGE_CAP;
    for (unsigned e = t; e < E; e += 1024){
        unsigned ed = eIn[e];
        atomicAdd(&zsh[ed >> 16], s1[ed & 0xFFFFu]);
    }
    __syncthreads();
    bool v0 = t < N,        v1 = t+1024 < N,  v2 = t+2048 < N,  v3 = t+3072 < N;
    uint c0 = v0 ? fcode(zsh[t])      : 0u;
    uint c1 = v1 ? fcode(zsh[t+1024]) : 0u;
    uint c2 = v2 ? fcode(zsh[t+2048]) : 0u;
    uint c3 = v3 ? fcode(zsh[t+3072]) : 0u;

    // --- exact k-th-largest code T via 3-pass radix (12/12/8 bits) ---------
    // pass-1 bins concentrate (shared sign/exponent) -> merge per-thread
    // duplicates before atomicAdd to cut same-bin LDS RMW serialization.
    for (int i = t; i < 4096; i += 1024) hist[i] = 0u;
    __syncthreads();
    if (v0){
        uint h0 = c0 >> 20, h1 = c1 >> 20, h2 = c2 >> 20, h3 = c3 >> 20;
        bool u1 = v1, u2 = v2, u3 = v3;
        uint n0 = 1;
        if (u1 && h1 == h0){ n0++; u1 = false; }
        if (u2 && h2 == h0){ n0++; u2 = false; }
        if (u3 && h3 == h0){ n0++; u3 = false; }
        atomicAdd(&hist[h0], n0);
        if (u1){
            uint n1 = 1;
            if (u2 && h2 == h1){ n1++; u2 = false; }
            if (u3 && h3 == h1){ n1++; u3 = false; }
            atomicAdd(&hist[h1], n1);
        }
        if (u2){
            uint n2 = 1;
            if (u3 && h3 == h2){ n2++; u3 = false; }
            atomicAdd(&hist[h2], n2);
        }
        if (u3) atomicAdd(&hist[h3], 1u);
    }
    __syncthreads();
    uint2 p1 = radix_scan(hist, wcnt, wbase, sh, t, lane, wv, (uint)k, 4096);
    uint B1 = p1.x; uint kk2 = (uint)k - p1.y;
    for (int i = t; i < 4096; i += 1024) hist[i] = 0u;
    __syncthreads();
    if (v0 && (c0 >> 20) == B1) atomicAdd(&hist[(c0 >> 8) & 0xFFFu], 1u);
    if (v1 && (c1 >> 20) == B1) atomicAdd(&hist[(c1 >> 8) & 0xFFFu], 1u);
    if (v2 && (c2 >> 20) == B1) atomicAdd(&hist[(c2 >> 8) & 0xFFFu], 1u);
    if (v3 && (c3 >> 20) == B1) atomicAdd(&hist[(c3 >> 8) & 0xFFFu], 1u);
    __syncthreads();
    uint2 p2 = radix_scan(hist, wcnt, wbase, sh, t, lane, wv, kk2, 4096);
    uint B2 = p2.x; uint kk3 = kk2 - p2.y;
    uint hi24 = (B1 << 12) | B2;
    for (int i = t; i < 256; i += 1024) hist[i] = 0u;
    __syncthreads();
    if (v0 && (c0 >> 8) == hi24) atomicAdd(&hist[c0 & 0xFFu], 1u);
    if (v1 && (c1 >> 8) == hi24) atomicAdd(&hist[c1 & 0xFFu], 1u);
    if (v2 && (c2 >> 8) == hi24) atomicAdd(&hist[c2 & 0xFFu], 1u);
    if (v3 && (c3 >> 8) == hi24) atomicAdd(&hist[c3 & 0xFFu], 1u);
    __syncthreads();
    uint2 p3 = radix_scan(hist, wcnt, wbase, sh, t, lane, wv, kk3, 256);
    uint T = (B1 << 20) | (B2 << 8) | p3.x;

    // --- compaction (strict > ranked, ties fill) ---------------------------
    ull b0 = __ballot(v0 && c0 > T), b1 = __ballot(v1 && c1 > T);
    ull b2 = __ballot(v2 && c2 > T), b3 = __ballot(v3 && c3 > T);
    uint t0 = (uint)__popcll(b0), t1 = (uint)__popcll(b1);
    uint t2 = (uint)__popcll(b2), t3 = (uint)__popcll(b3);
    if (lane == 0) wcnt[wv] = t0 + t1 + t2 + t3;
    __syncthreads();
    if (t == 0){
        uint s = 0;
        for (int i = 0; i < 16; i++){ wbase[i] = s; s += wcnt[i]; }
        sh[1] = s;
    }
    __syncthreads();
    uint cntGT = sh[1];
    uint rem = (uint)k - cntGT;
    ull ltm = ((ull)1 << lane) - 1;
    uint off = wbase[wv];
    if (v0 && c0 > T){ uint r = off + (uint)__popcll(b0 & ltm); int i = t;
        perm[r] = i; svals[r] = tanhf(zsh[i]); rnk[i] = (int)r; }
    off += t0;
    if (v1 && c1 > T){ uint r = off + (uint)__popcll(b1 & ltm); int i = t+1024;
        perm[r] = i; svals[r] = tanhf(zsh[i]); rnk[i] = (int)r; }
    off += t1;
    if (v2 && c2 > T){ uint r = off + (uint)__popcll(b2 & ltm); int i = t+2048;
        perm[r] = i; svals[r] = tanhf(zsh[i]); rnk[i] = (int)r; }
    off += t2;
    if (v3 && c3 > T){ uint r = off + (uint)__popcll(b3 & ltm); int i = t+3072;
        perm[r] = i; svals[r] = tanhf(zsh[i]); rnk[i] = (int)r; }
    #pragma unroll
    for (int j = 0; j < 4; j++){
        int i = t + j*1024;
        bool vv = (j==0) ? v0 : (j==1) ? v1 : (j==2) ? v2 : v3;
        uint cc = (j==0) ? c0 : (j==1) ? c1 : (j==2) ? c2 : c3;
        if (vv && cc == T){
            uint e = atomicAdd(&sh[2], 1u);
            if (e < rem){
                uint r = cntGT + e;
                perm[r] = i; svals[r] = tanhf(zsh[i]); rnk[i] = (int)r;
            }
        }
    }
    __syncthreads();
    if (slotOut >= 0){
        for (unsigned e = t; e < E; e += 1024){
            unsigned ed = eIn[e];
            int nd = rnk[ed >> 16], ns = rnk[ed & 0xFFFFu];
            if (nd >= 0 && ns >= 0){
                unsigned idx = atomicAdd(&ecnt[slotOut], 1u);
                if (idx < EDGE_CAP){
                    eOut[idx] = ((unsigned)nd << 16) | (unsigned)ns;
                    atomicAdd(&degN[nd], 1.0f);
                }
            }
        }
    }
}

// ---------------- layer-3 pool+readout (fp32-exact) + fused writeout -------
__global__ __launch_bounds__(256) void k_poolread3(const float* __restrict__ Xn,
        const int* __restrict__ perm, const float* __restrict__ svals, int k,
        uint* __restrict__ maxU, float* __restrict__ sums,
        unsigned* __restrict__ done, float* __restrict__ out){
    int b = blockIdx.x, t = threadIdx.x;
    float m = -INFINITY, s = 0.f;
    for (int r = b; r < k; r += 64){
        int p = perm[r];
        float v = Xn[p*NH + t] * svals[r];
        m = fmaxf(m, v); s += v;
    }
    atomicMax(&maxU[2*NH + t], fcode(m));
    atomicAdd(&sums[2*NH + t], s);
    __threadfence();
    __shared__ uint lastv;
    if (t == 0) lastv = atomicAdd(done, 1u);
    __syncthreads();
    if (lastv == 63u){
        // final combine; atomic loads for cross-XCD visibility
        uint m0 = atomicAdd(&maxU[t], 0u);
        uint m1 = atomicAdd(&maxU[NH + t], 0u);
        uint m2 = atomicAdd(&maxU[2*NH + t], 0u);
        float s0 = atomicAdd(&sums[t], 0.f);
        float s1v = atomicAdd(&sums[NH + t], 0.f);
        float s2 = atomicAdd(&sums[2*NH + t], 0.f);
        out[t] = fdecode(m0) + fdecode(m1) + fdecode(m2);
        out[NH + t] = s0*(1.0f/KL1) + s1v*(1.0f/KL2) + s2*(1.0f/KL3);
    }
}

// =======================================================================
extern "C" void kernel_launch(void* const* d_in, const int* in_sizes, int n_in,
                              void* d_out, int out_size, void* d_ws, size_t ws_size,
                              hipStream_t stream)
{
    const void* b1 = d_in[5];
    const void* b2 = d_in[7];
    const void* b3 = d_in[9];
    const void* Wr1 = d_in[10]; const void* Wn1 = d_in[11]; const void* bs1 = d_in[12];
    const void* Wr2 = d_in[13]; const void* Wn2 = d_in[14]; const void* bs2 = d_in[15];
    const void* Wr3 = d_in[16]; const void* Wn3 = d_in[17]; const void* bs3 = d_in[18];

    char* w = (char*)d_ws;
    auto alloc = [&](size_t bytes)->char*{ char* p = w; w += (bytes + 255) & ~(size_t)255; return p; };
    ushort*   Xb    = (ushort*)  alloc((size_t)NN*DIN*2);
    float*    Xn    = (float*)   alloc((size_t)NN*NH*4);
    float*    XW    = (float*)   alloc((size_t)NN*NH*4);
    ushort*   Wb    = (ushort*)  alloc((size_t)262144*2);
    unsigned* E0    = (unsigned*)alloc((size_t)EDGE_CAP*4);
    unsigned* E1    = (unsigned*)alloc((size_t)EDGE_CAP*4);
    float*    tmin  = (float*)   alloc(4096*4);
    float*    sq    = (float*)   alloc(NN*4);
    float*    degA  = (float*)   alloc(NN*4);
    float*    degB  = (float*)   alloc(NN*4);
    float*    s1    = (float*)   alloc(NN*4);
    float*    z     = (float*)   alloc(NN*4);
    int*      perm  = (int*)     alloc(NN*4);
    float*    svals = (float*)   alloc(NN*4);
    unsigned* ecnt  = (unsigned*)alloc(256);
    unsigned* maxd2 = (unsigned*)alloc(256);
    unsigned* dflag = (unsigned*)alloc(256);
    uint*     maxU  = (uint*)    alloc(768*4);
    float*    sums  = (float*)   alloc(768*4);
    (void)ws_size;

    DtIn da;
    for (int i = 0; i < 19; i++){ da.p[i] = d_in[i]; da.n[i] = in_sizes[i]; }

    k_prep<<<NN + 65, 512, 0, stream>>>(da, Xb, sq, Wb, dflag, degA, maxU, sums,
            ecnt, maxd2, tmin);
    // gram pass 1: 256 fused XW tiles + 2080 triangle tiles (64x64, 1D grid)
    k_gram<1><<<256 + NTRI, 256, 0, stream>>>(Xb, sq, maxd2, tmin, ecnt, E0, degA,
            Wb, XW);
    k_gram<2><<<NTRI, 256, 0, stream>>>(Xb, sq, maxd2, tmin, ecnt, E0, degA,
            Wb, XW);

    // ---------------- layer 1 (N=4096 -> k=3072) ----------------
    k_gcnscore<<<NN, 256, 0, stream>>>(XW, E0, ecnt, 0, degA, b1, Wn1, Wr1, bs1,
            dflag+5, dflag+11, dflag+10, dflag+12, Xn, s1, z);
    k_select<<<1, 1024, 0, stream>>>(z, s1, NN, KL1, E0, ecnt, 0, E1, 1,
            perm, svals, degB, KL1);

    // ---------------- layer 2 (N=3072 -> k=2304); fused pool1+readout ------
    k_xwp<<<dim3(48,4), 256, 0, stream>>>(Xn, perm, svals, Wb + 131072, XW, KL1,
            maxU, sums, 0);
    k_gcnscore<<<KL1, 256, 0, stream>>>(XW, E1, ecnt, 1, degB, b2, Wn2, Wr2, bs2,
            dflag+7, dflag+14, dflag+13, dflag+15, Xn, s1, z);
    k_select<<<1, 1024, 0, stream>>>(z, s1, KL1, KL2, E1, ecnt, 1, E0, 2,
            perm, svals, degA, KL2);

    // ---------------- layer 3 (N=2304 -> k=1728); fused pool2+readout ------
    k_xwp<<<dim3(36,4), 256, 0, stream>>>(Xn, perm, svals, Wb + 196608, XW, KL2,
            maxU, sums, 1);
    k_gcnscore<<<KL2, 256, 0, stream>>>(XW, E0, ecnt, 2, degA, b3, Wn3, Wr3, bs3,
            dflag+9, dflag+17, dflag+16, dflag+18, Xn, s1, z);
    k_select<<<1, 1024, 0, stream>>>(z, s1, KL2, KL3, E0, ecnt, 2,
            (unsigned*)nullptr, -1, perm, svals, degB, 0);
    k_poolread3<<<64, 256, 0, stream>>>(Xn, perm, svals, KL3, maxU, sums,
            ecnt + 3, (float*)d_out);
}

// Round 9
// 212.741 us; speedup vs baseline: 3.6749x; 1.0881x over previous
//
#include <hip/hip_runtime.h>
#include <hip/hip_bf16.h>
#include <math.h>

typedef __hip_bfloat16 bf16;
typedef unsigned short ushort;
typedef unsigned int uint;
typedef unsigned long long ull;
static __device__ __forceinline__ float b2f(bf16 x){ return __bfloat162float(x); }

static __device__ __forceinline__ float ldf(const void* p, int i, int isbf){
    return isbf ? b2f(((const bf16*)p)[i]) : ((const float*)p)[i];
}
static __device__ __forceinline__ ushort f2b(float x){
    return __bfloat16_as_ushort(__float2bfloat16(x));
}
static __device__ __forceinline__ uint fcode(float v){
    uint u = __float_as_uint(v);
    return (u & 0x80000000u) ? ~u : (u | 0x80000000u);
}
static __device__ __forceinline__ float fdecode(uint c){
    uint u = (c & 0x80000000u) ? (c & 0x7FFFFFFFu) : ~c;
    return __uint_as_float(u);
}

#define NN    4096
#define FEAT0 500
#define DIN   512
#define NH    256
#define KL1   3072
#define KL2   2304
#define KL3   1728
#define EDGE_CAP 786432u
#define NT128 528    // 32*33/2 lower-triangle tiles at 128x128

typedef __attribute__((ext_vector_type(8)))  short v8s;
typedef __attribute__((ext_vector_type(16))) float v16f;

// async global->LDS, 16B/lane. LDS dest is wave-uniform base + lane*16;
// global src is per-lane (pre-swizzled to preserve the XOR LDS layout).
static __device__ __forceinline__ void gl_lds16(const ushort* g, ushort* l){
    __builtin_amdgcn_global_load_lds(
        (const __attribute__((address_space(1))) void*)g,
        (__attribute__((address_space(3))) void*)l, 16, 0, 0);
}

// ---------------- prep: pos MLP + concat + W-convert + ALL inits -----------
// blocks [0,NN): rows; [NN,NN+64): W1|W2|W3 -> bf16; block NN+64: inits+dflag
struct DtIn { const void* p[19]; int n[19]; };
static __device__ __forceinline__ void detect_bf16(const void* p, int n, int t,
        uint* flag){
    if (t < 256 && t < n){
        uint e = ((uint)((const ushort*)p)[t] >> 7) & 0xFFu;
        if (e >= 135u) atomicAnd(flag, 0u);
    }
}
__global__ __launch_bounds__(512) void k_prep(DtIn da,
        ushort* __restrict__ Xb, float* __restrict__ sq, ushort* __restrict__ Wb,
        unsigned* __restrict__ dflag, float* __restrict__ degA,
        uint* __restrict__ maxU, float* __restrict__ sums,
        unsigned* __restrict__ ecnt, unsigned* __restrict__ maxd2,
        float* __restrict__ tmin){
    int row = blockIdx.x, t = threadIdx.x;
    if (row < NN){
        __shared__ uint fl[4];
        if (t < 4) fl[t] = 1u;
        __syncthreads();
        detect_bf16(da.p[0], da.n[0], t, &fl[0]);   // feature
        detect_bf16(da.p[1], da.n[1], t, &fl[1]);   // img
        detect_bf16(da.p[2], da.n[2], t, &fl[2]);   // Wpos
        detect_bf16(da.p[3], da.n[3], t, &fl[3]);   // bpos
        __syncthreads();
        int f_feat = (int)fl[0], f_img = (int)fl[1], f_wp = (int)fl[2], f_bp = (int)fl[3];
        float v;
        if (t < FEAT0) v = ldf(da.p[0], row*FEAT0 + t, f_feat);
        else {
            int c = t - FEAT0;
            float acc = ldf(da.p[3], c, f_bp);
            #pragma unroll
            for (int d = 0; d < 6; d++)
                acc += ldf(da.p[1], row*6+d, f_img) * ldf(da.p[2], d*12+c, f_wp);
            v = fmaxf(acc, 0.f);
        }
        bf16 vb = __float2bfloat16(v);
        Xb[row*DIN + t] = __bfloat16_as_ushort(vb);
        float vr = b2f(vb);                 // sq of rounded vector -> d2 exact
        float vsq = vr*vr;
        #pragma unroll
        for (int off = 32; off >= 1; off >>= 1) vsq += __shfl_down(vsq, off);
        __shared__ float red[8];
        if ((t & 63) == 0) red[t >> 6] = vsq;
        __syncthreads();
        if (t == 0){
            float sres = 0.f;
            #pragma unroll
            for (int i = 0; i < 8; i++) sres += red[i];
            sq[row] = sres;
        }
    } else if (row < NN + 64){
        __shared__ uint fl[3];
        if (t < 3) fl[t] = 1u;
        __syncthreads();
        detect_bf16(da.p[4], da.n[4], t, &fl[0]);   // W1
        detect_bf16(da.p[6], da.n[6], t, &fl[1]);   // W2
        detect_bf16(da.p[8], da.n[8], t, &fl[2]);   // W3
        __syncthreads();
        int i0 = ((row - NN)*512 + t)*8;
        #pragma unroll
        for (int j = 0; j < 8; j++){
            int idx = i0 + j;
            float v;
            if (idx < 131072)       v = ldf(da.p[4], idx,          (int)fl[0]);
            else if (idx < 196608)  v = ldf(da.p[6], idx - 131072, (int)fl[1]);
            else                    v = ldf(da.p[8], idx - 196608, (int)fl[2]);
            Wb[idx] = __bfloat16_as_ushort(__float2bfloat16(v));
        }
    } else {
        // inits + parallel dflag scan (all 512 threads; R8-verified)
        __shared__ uint fl19[19];
        if (t < 19) fl19[t] = 1u;
        for (int i = t; i < NN; i += 512) degA[i] = 1.0f;
        for (int i = t; i < 4096; i += 512) tmin[i] = INFINITY;
        for (int i = t; i < 768; i += 512){ maxU[i] = 0x007FFFFFu; sums[i] = 0.f; }
        if (t == 0){
            #pragma unroll
            for (int i = 0; i < 8; i++) ecnt[i] = 0u;
            maxd2[0] = 0u;
        }
        __syncthreads();
        for (int idx = t; idx < 19*256; idx += 512){
            int i = idx >> 8, j = idx & 255;
            if (j < da.n[i]){
                uint e = ((uint)((const ushort*)da.p[i])[j] >> 7) & 0xFFu;
                if (e >= 135u) atomicAnd(&fl19[i], 0u);
            }
        }
        __syncthreads();
        if (t < 19) dflag[t] = fl19[t];
    }
}

// ---- 128x128 MFMA tile of A·B^T, 512 threads (8 waves, 4x2), gl_lds staged.
// Wave w stages rows [w*16, w*16+16) of both A and B per K-step; computes
// acc tiles (rows wr*32..+32) x (cols wc*64+{0,32}..+32). Per-element
// K-accumulation order (outer 64-step, inner ks) identical to the 64x64
// version -> bit-identical d2. acc = 2 x v16f = 32 VGPR (spill-safe).
struct A2 { v16f a0; v16f a1; };
static __device__ __forceinline__ A2 mm_tile128(const ushort* __restrict__ Arows,
        const ushort* __restrict__ Brows, ushort* As, ushort* Bs, int tid){
    int lane = tid & 63, wv = tid >> 6;
    int l31 = lane & 31, hi = lane >> 5;
    int ro = lane >> 3, cch = lane & 7;
    int r0 = wv*16 + ro, r1 = wv*16 + 8 + ro;
    const ushort* gA0 = Arows + (size_t)r0*DIN + ((cch ^ (r0&7))<<3);
    const ushort* gA1 = Arows + (size_t)r1*DIN + ((cch ^ (r1&7))<<3);
    const ushort* gB0 = Brows + (size_t)r0*DIN + ((cch ^ (r0&7))<<3);
    const ushort* gB1 = Brows + (size_t)r1*DIN + ((cch ^ (r1&7))<<3);
    ushort* lA0 = As + (wv*16)*64;
    ushort* lA1 = As + (wv*16+8)*64;
    ushort* lB0 = Bs + (wv*16)*64;
    ushort* lB1 = Bs + (wv*16+8)*64;
    int wr = wv >> 1, wc = wv & 1;
    int ar = wr*32 + l31;             // A row for this lane
    int br0 = wc*64 + l31;            // B rows (= output cols), sc = 0
    int br1 = wc*64 + 32 + l31;       //                          sc = 1
    int ra  = ar*64,  f7a = ar & 7;
    int rb0 = br0*64, f7b0 = br0 & 7;
    int rb1 = br1*64, f7b1 = br1 & 7;
    v16f acc0 = {}, acc1 = {};
    for (int c = 0; c < DIN/64; c++){
        int k0 = c*64;
        __syncthreads();                 // previous MFMA reads done
        gl_lds16(gA0 + k0, lA0);
        gl_lds16(gA1 + k0, lA1);
        gl_lds16(gB0 + k0, lB0);
        gl_lds16(gB1 + k0, lB1);
        __syncthreads();                 // vmcnt drained -> tile resident
        #pragma unroll
        for (int ks = 0; ks < 4; ks++){
            int gq = ks*2 + hi;
            v8s a  = *(const v8s*)&As[ra  + ((gq^f7a )<<3)];
            v8s b0 = *(const v8s*)&Bs[rb0 + ((gq^f7b0)<<3)];
            v8s b1 = *(const v8s*)&Bs[rb1 + ((gq^f7b1)<<3)];
            acc0 = __builtin_amdgcn_mfma_f32_32x32x16_bf16(a, b0, acc0, 0, 0, 0);
            acc1 = __builtin_amdgcn_mfma_f32_32x32x16_bf16(a, b1, acc1, 0, 0, 0);
        }
    }
    A2 r; r.a0 = acc0; r.a1 = acc1;
    return r;
}

// ---- layer-1 X @ W, 128x64 tile at 512 threads (A via gl_lds, W scattered).
static __device__ __forceinline__ void xw_body128(const ushort* __restrict__ Ab,
        const ushort* __restrict__ Wb, float* __restrict__ XW, int rb, int cb,
        ushort* As, ushort* Bs){
    int tid = threadIdx.x, lane = tid & 63, wv = tid >> 6;
    int l31 = lane & 31, hi = lane >> 5;
    int ro = lane >> 3, cch = lane & 7;
    int r0 = wv*16 + ro, r1 = wv*16 + 8 + ro;
    const ushort* Arows = Ab + (size_t)rb*128*DIN;
    const ushort* gA0 = Arows + (size_t)r0*DIN + ((cch ^ (r0&7))<<3);
    const ushort* gA1 = Arows + (size_t)r1*DIN + ((cch ^ (r1&7))<<3);
    ushort* lA0 = As + (wv*16)*64;
    ushort* lA1 = As + (wv*16+8)*64;
    // W scatter: thread (kr = tid>>3 in [0,64), ch = tid&7) handles 8 cols
    int kr = tid >> 3, ch = tid & 7;
    int kg = kr >> 3, k7 = kr & 7;
    float4 wv4 = *(const float4*)(Wb + (size_t)kr*NH + cb*64 + ch*8);
    int wr = wv >> 1, wc = wv & 1;
    int ar = wr*32 + l31;
    int brr = wc*32 + l31;
    int ra = ar*64,  f7a = ar & 7;
    int rbp = brr*64, f7b = brr & 7;
    v16f acc = {};
    for (int c = 0; c < DIN/64; c++){
        __syncthreads();
        gl_lds16(gA0 + c*64, lA0);
        gl_lds16(gA1 + c*64, lA1);
        {
            const ushort* ws = (const ushort*)&wv4;
            #pragma unroll
            for (int j = 0; j < 8; j++){
                int nn = ch*8 + j;
                Bs[nn*64 + ((kg^(nn&7))<<3) + k7] = ws[j];
            }
        }
        __syncthreads();
        if (c + 1 < DIN/64)
            wv4 = *(const float4*)(Wb + (size_t)((c+1)*64+kr)*NH + cb*64 + ch*8);
        #pragma unroll
        for (int ks = 0; ks < 4; ks++){
            int gq = ks*2 + hi;
            v8s a = *(const v8s*)&As[ra  + ((gq^f7a)<<3)];
            v8s b = *(const v8s*)&Bs[rbp + ((gq^f7b)<<3)];
            acc = __builtin_amdgcn_mfma_f32_32x32x16_bf16(a, b, acc, 0, 0, 0);
        }
    }
    int n  = cb*64 + wc*32 + l31;
    int mb = rb*128 + wr*32 + 4*hi;
    #pragma unroll
    for (int i = 0; i < 16; i++){
        int m = mb + (i&3) + 8*(i>>2);
        XW[(size_t)m*NH + n] = acc[i];
    }
}

// ---------------- Gram via MFMA, 128x128 tiles, triangular 1D grid ---------
// PASS 1: blocks [0,128) = fused layer-1 XW tiles (128x64); [128,128+NT128) =
//         triangle. PASS 2: blocks [0,NT128).
template<int PASS>
__global__ __launch_bounds__(512, 4) void k_gram(const ushort* __restrict__ Xb,
        const float* __restrict__ sq, unsigned* __restrict__ maxd2,
        float* __restrict__ tmin, unsigned* __restrict__ ecnt,
        unsigned* __restrict__ edges, float* __restrict__ deg,
        const ushort* __restrict__ Wb, float* __restrict__ XW){
    __shared__ __align__(16) ushort As[128*64];
    __shared__ __align__(16) ushort Bs[128*64];
    int b = blockIdx.x;
    if (PASS == 1){
        if (b < 128){
            xw_body128(Xb, Wb, XW, b >> 2, b & 3, As, Bs);
            return;
        }
        b -= 128;
    }
    // triangular decode over 32x32 tile grid: b -> (rb, cb), cb <= rb
    float ff = sqrtf(8.f*(float)b + 1.f);
    int rb = (int)((ff - 1.f) * 0.5f);
    while ((rb+1)*(rb+2)/2 <= b) rb++;
    while (rb*(rb+1)/2 > b) rb--;
    int cb = b - rb*(rb+1)/2;

    int tid = threadIdx.x;
    float tthr = 0.f;
    if (PASS == 2){
        tthr = 0.5f * __uint_as_float(maxd2[0]);
        if (tmin[rb*32 + cb] >= tthr) return;   // block-uniform skip (exact bound)
    }
    int lane = tid & 63, wv = tid >> 6;
    int l31 = lane & 31, hi = lane >> 5;
    int wr = wv >> 1, wc = wv & 1;
    A2 acc = mm_tile128(Xb + (size_t)rb*128*DIN, Xb + (size_t)cb*128*DIN,
                        As, Bs, tid);
    int rbase = rb*128 + wr*32 + 4*hi;
    int col0  = cb*128 + wc*64 + l31;
    int col1  = col0 + 32;
    float sqc0 = sq[col0], sqc1 = sq[col1];
    if (PASS == 1){
        float m = 0.f, mn = INFINITY;
        #pragma unroll
        for (int i = 0; i < 16; i++){
            int r = rbase + (i&3) + 8*(i>>2);
            float d20 = sq[r] + sqc0 - 2.f*acc.a0[i];
            float d21 = sq[r] + sqc1 - 2.f*acc.a1[i];
            if (r != col0) m = fmaxf(m, d20);
            if (r >  col0) mn = fminf(mn, d20);
            if (r != col1) m = fmaxf(m, d21);
            if (r >  col1) mn = fminf(mn, d21);
        }
        #pragma unroll
        for (int off = 32; off >= 1; off >>= 1){
            m  = fmaxf(m,  __shfl_down(m,  off));
            mn = fminf(mn, __shfl_down(mn, off));
        }
        __shared__ float wmax[8], wmin[8];
        if (lane == 0){ wmax[wv] = m; wmin[wv] = mn; }
        __syncthreads();
        if (tid == 0){
            float mm = wmax[0], mmn = wmin[0];
            #pragma unroll
            for (int i = 1; i < 8; i++){
                mm = fmaxf(mm, wmax[i]); mmn = fminf(mmn, wmin[i]);
            }
            tmin[rb*32 + cb] = mmn;
            atomicMax(maxd2, __float_as_uint(fmaxf(mm, 0.f)));  // non-neg: uint order ok
        }
    } else {
        #pragma unroll
        for (int i = 0; i < 16; i++){
            int r = rbase + (i&3) + 8*(i>>2);
            float d20 = sq[r] + sqc0 - 2.f*acc.a0[i];
            if (r > col0 && d20 < tthr){
                unsigned idx = atomicAdd(ecnt, 1u);
                if (idx < EDGE_CAP){
                    edges[idx] = ((unsigned)r << 16) | (unsigned)col0;  // dst<<16|src
                    atomicAdd(&deg[r], 1.0f);
                }
            }
            float d21 = sq[r] + sqc1 - 2.f*acc.a1[i];
            if (r > col1 && d21 < tthr){
                unsigned idx = atomicAdd(ecnt, 1u);
                if (idx < EDGE_CAP){
                    edges[idx] = ((unsigned)r << 16) | (unsigned)col1;
                    atomicAdd(&deg[r], 1.0f);
                }
            }
        }
    }
}

// ---------------- fused pool + X@W + prev-layer readout (layers 2,3) -------
__global__ __launch_bounds__(256) void k_xwp(const float* __restrict__ Xn,
        const int* __restrict__ perm, const float* __restrict__ svals,
        const ushort* __restrict__ Wb, float* __restrict__ XW, int M,
        uint* __restrict__ maxU, float* __restrict__ sums, int layer){
    int rb = blockIdx.x, cb = blockIdx.y;     // grid (M/64, 4); K = NH = 256
    __shared__ __align__(16) ushort As[64*64];
    __shared__ __align__(16) ushort Bs[64*64];
    __shared__ float pmx[256], psm[256];
    int tid = threadIdx.x, lane = tid & 63, wv = tid >> 6;
    int wwr = wv >> 1, wwc = wv & 1;
    int l31 = lane & 31, hi = lane >> 5;
    int arow0 = tid >> 3, ag = tid & 7;
    int arow1 = arow0 + 32;
    int da0 = arow0*64 + ((ag^(arow0&7))<<3);
    int da1 = arow1*64 + ((ag^(arow1&7))<<3);
    int p0 = perm[rb*64 + arow0]; float sv0 = svals[rb*64 + arow0];
    int p1 = perm[rb*64 + arow1]; float sv1 = svals[rb*64 + arow1];
    int kr = tid >> 2, ng = tid & 3;
    int kg = kr >> 3, k7 = kr & 7;
    int ra0 = (wwr*32 + l31)*64, rbp = (wwc*32 + l31)*64;
    int fr7a = (wwr*32 + l31) & 7, fr7b = (wwc*32 + l31) & 7;

    float4 xa0 = *(const float4*)(Xn + (size_t)p0*NH + ag*8);
    float4 xa1 = *(const float4*)(Xn + (size_t)p0*NH + ag*8 + 4);
    float4 xb0 = *(const float4*)(Xn + (size_t)p1*NH + ag*8);
    float4 xb1 = *(const float4*)(Xn + (size_t)p1*NH + ag*8 + 4);
    float4 wb0 = *(const float4*)(Wb + (size_t)kr*NH + cb*64 + ng*16);
    float4 wb1 = *(const float4*)(Wb + (size_t)kr*NH + cb*64 + ng*16 + 8);

    v16f acc = {};
    for (int c = 0; c < 4; c++){
        __syncthreads();
        {
            __align__(16) ushort ta[8];
            ta[0]=f2b(xa0.x*sv0); ta[1]=f2b(xa0.y*sv0); ta[2]=f2b(xa0.z*sv0); ta[3]=f2b(xa0.w*sv0);
            ta[4]=f2b(xa1.x*sv0); ta[5]=f2b(xa1.y*sv0); ta[6]=f2b(xa1.z*sv0); ta[7]=f2b(xa1.w*sv0);
            *(float4*)&As[da0] = *(const float4*)ta;
            __align__(16) ushort tb[8];
            tb[0]=f2b(xb0.x*sv1); tb[1]=f2b(xb0.y*sv1); tb[2]=f2b(xb0.z*sv1); tb[3]=f2b(xb0.w*sv1);
            tb[4]=f2b(xb1.x*sv1); tb[5]=f2b(xb1.y*sv1); tb[6]=f2b(xb1.z*sv1); tb[7]=f2b(xb1.w*sv1);
            *(float4*)&As[da1] = *(const float4*)tb;
        }
        {
            const ushort* bw0 = (const ushort*)&wb0;
            const ushort* bw1 = (const ushort*)&wb1;
            #pragma unroll
            for (int j = 0; j < 8; j++){
                int nn = ng*16 + j;
                Bs[nn*64 + ((kg^(nn&7))<<3) + k7] = bw0[j];
            }
            #pragma unroll
            for (int j = 0; j < 8; j++){
                int nn = ng*16 + 8 + j;
                Bs[nn*64 + ((kg^(nn&7))<<3) + k7] = bw1[j];
            }
        }
        __syncthreads();
        if (c < 3){
            int k0 = (c+1)*64;
            xa0 = *(const float4*)(Xn + (size_t)p0*NH + k0 + ag*8);
            xa1 = *(const float4*)(Xn + (size_t)p0*NH + k0 + ag*8 + 4);
            xb0 = *(const float4*)(Xn + (size_t)p1*NH + k0 + ag*8);
            xb1 = *(const float4*)(Xn + (size_t)p1*NH + k0 + ag*8 + 4);
            wb0 = *(const float4*)(Wb + (size_t)(k0+kr)*NH + cb*64 + ng*16);
            wb1 = *(const float4*)(Wb + (size_t)(k0+kr)*NH + cb*64 + ng*16 + 8);
        }
        if (cb == 0){
            int cc = tid & 63, q = tid >> 6;
            int gg = cc >> 3, c7 = cc & 7;
            float m = -INFINITY, s = 0.f;
            #pragma unroll
            for (int i = 0; i < 16; i++){
                int rr = q*16 + i;
                float v = __uint_as_float(((uint)As[rr*64 + ((gg^(rr&7))<<3) + c7]) << 16);
                m = fmaxf(m, v); s += v;
            }
            pmx[tid] = m; psm[tid] = s;
            __syncthreads();
            if (tid < 64){
                float mm = fmaxf(fmaxf(pmx[tid], pmx[tid+64]), fmaxf(pmx[tid+128], pmx[tid+192]));
                float ss = psm[tid] + psm[tid+64] + psm[tid+128] + psm[tid+192];
                atomicMax(&maxU[layer*NH + c*64 + tid], fcode(mm));
                atomicAdd(&sums[layer*NH + c*64 + tid], ss);
            }
        }
        #pragma unroll
        for (int ks = 0; ks < 4; ks++){
            int gq = ks*2 + hi;
            v8s a = *(const v8s*)&As[ra0 + ((gq^fr7a)<<3)];
            v8s b = *(const v8s*)&Bs[rbp + ((gq^fr7b)<<3)];
            acc = __builtin_amdgcn_mfma_f32_32x32x16_bf16(a, b, acc, 0, 0, 0);
        }
    }
    int n  = cb*64 + wwc*32 + l31;
    int mb = rb*64 + wwr*32 + 4*hi;
    #pragma unroll
    for (int i = 0; i < 16; i++){
        int m = mb + (i&3) + 8*(i>>2);
        XW[(size_t)m*NH + n] = acc[i];
    }
}

// ---- fused GCN finish: edge-scan aggregation + relu + scorer --------------
__global__ __launch_bounds__(256) void k_gcnscore(const float* __restrict__ XW,
        const unsigned* __restrict__ edges, const unsigned* __restrict__ ecnt, int slot,
        const float* __restrict__ deg, const void* __restrict__ b,
        const void* __restrict__ Wn, const void* __restrict__ Wr, const void* __restrict__ bs,
        const unsigned* __restrict__ fb, const unsigned* __restrict__ fWn,
        const unsigned* __restrict__ fWr, const unsigned* __restrict__ fbs,
        float* __restrict__ Xn, float* __restrict__ s1, float* __restrict__ z){
    int row = blockIdx.x, t = threadIdx.x;
    __shared__ unsigned eL[256];
    __shared__ unsigned Esh;
    if (t == 0){ unsigned E0 = ecnt[slot]; Esh = (E0 > EDGE_CAP) ? EDGE_CAP : E0; }
    __syncthreads();
    unsigned E = Esh;
    float disr = 1.0f / sqrtf(deg[row]);
    float acc = disr * XW[row*NH + t];
    for (unsigned base = 0; base < E; base += 256){
        unsigned nchunk = E - base; if (nchunk > 256) nchunk = 256;
        __syncthreads();
        if (t < nchunk) eL[t] = edges[base + t];
        __syncthreads();
        for (unsigned j = 0; j < nchunk; j++){
            unsigned ed = eL[j];
            if ((int)(ed >> 16) == row){
                int src = ed & 0xFFFFu;
                acc += (1.0f / sqrtf(deg[src])) * XW[src*NH + t];
            }
        }
    }
    float xn = fmaxf(fmaf(disr, acc, ldf(b, t, (int)fb[0])), 0.f);
    Xn[row*NH + t] = xn;
    float a  = xn * ldf(Wn, t, (int)fWn[0]);
    float bb = xn * ldf(Wr, t, (int)fWr[0]);
    for (int off = 32; off >= 1; off >>= 1){ a += __shfl_down(a, off); bb += __shfl_down(bb, off); }
    __shared__ float ra[4], rbv[4];
    int w = t >> 6;
    if ((t & 63) == 0){ ra[w] = a; rbv[w] = bb; }
    __syncthreads();
    if (t == 0){
        s1[row] = ra[0]+ra[1]+ra[2]+ra[3];
        z[row]  = rbv[0]+rbv[1]+rbv[2]+rbv[3] + ldf(bs, 0, (int)fbs[0]);
    }
}

// ---- radix-select helper: suffix-scan a shared histogram, find the bucket
// containing the kk-th largest element. Returns (bucket, count strictly above).
static __device__ __forceinline__ uint2 radix_scan(const uint* hist, uint* wt,
        uint* ws, uint* sh, int t, int lane, int wv, uint kk, int NB){
    uint loc = 0;
    int b0 = t << 2;
    if (b0 < NB) loc = hist[b0] + hist[b0+1] + hist[b0+2] + hist[b0+3];
    uint s = loc;
    #pragma unroll
    for (int off = 1; off < 64; off <<= 1){
        uint u = __shfl_down(s, off);
        if (lane + off < 64) s += u;
    }
    if (lane == 0) wt[wv] = s;               // wave total (inclusive suffix @lane0)
    __syncthreads();
    if (t < 16){
        uint a = 0;
        for (int j = t + 1; j < 16; j++) a += wt[j];
        ws[t] = a;                           // count in waves above
    }
    __syncthreads();
    if (b0 < NB){
        uint run = ws[wv] + (s - loc);       // count in bins strictly above my group
        for (int b = b0 + 3; b >= b0; b--){
            uint h = hist[b];
            if (run < kk && run + h >= kk){ sh[0] = (uint)b; sh[1] = run; }
            run += h;
        }
    }
    __syncthreads();
    return make_uint2(sh[0], sh[1]);
}

// ---------------- fused: scoredge + radix top-k select + efilter -----------
__global__ __launch_bounds__(1024) void k_select(const float* __restrict__ z,
        const float* __restrict__ s1, int N, int k,
        const unsigned* __restrict__ eIn, unsigned* __restrict__ ecnt, int slotCur,
        unsigned* __restrict__ eOut, int slotOut,
        int* __restrict__ perm, float* __restrict__ svals,
        float* __restrict__ degN, int Nnext){
    __shared__ float zsh[4096];
    __shared__ int   rnk[4096];
    __shared__ uint  hist[4096];
    __shared__ uint  wcnt[16];
    __shared__ uint  wbase[16];
    __shared__ uint  sh[4];
    int t = threadIdx.x;
    int lane = t & 63, wv = t >> 6;
    for (int i = t; i < N; i += 1024){ zsh[i] = z[i]; rnk[i] = -1; }
    for (int i = t; i < Nnext; i += 1024) degN[i] = 1.0f;
    if (t == 0) sh[2] = 0u;
    __syncthreads();
    unsigned E = ecnt[slotCur]; if (E > EDGE_CAP) E = EDGE_CAP;
    for (unsigned e = t; e < E; e += 1024){
        unsigned ed = eIn[e];
        atomicAdd(&zsh[ed >> 16], s1[ed & 0xFFFFu]);
    }
    __syncthreads();
    bool v0 = t < N,        v1 = t+1024 < N,  v2 = t+2048 < N,  v3 = t+3072 < N;
    uint c0 = v0 ? fcode(zsh[t])      : 0u;
    uint c1 = v1 ? fcode(zsh[t+1024]) : 0u;
    uint c2 = v2 ? fcode(zsh[t+2048]) : 0u;
    uint c3 = v3 ? fcode(zsh[t+3072]) : 0u;

    // --- exact k-th-largest code T via 3-pass radix (12/12/8 bits) ---------
    // pass-1 bins concentrate (shared sign/exponent) -> merge per-thread
    // duplicates before atomicAdd to cut same-bin LDS RMW serialization.
    for (int i = t; i < 4096; i += 1024) hist[i] = 0u;
    __syncthreads();
    if (v0){
        uint h0 = c0 >> 20, h1 = c1 >> 20, h2 = c2 >> 20, h3 = c3 >> 20;
        bool u1 = v1, u2 = v2, u3 = v3;
        uint n0 = 1;
        if (u1 && h1 == h0){ n0++; u1 = false; }
        if (u2 && h2 == h0){ n0++; u2 = false; }
        if (u3 && h3 == h0){ n0++; u3 = false; }
        atomicAdd(&hist[h0], n0);
        if (u1){
            uint n1 = 1;
            if (u2 && h2 == h1){ n1++; u2 = false; }
            if (u3 && h3 == h1){ n1++; u3 = false; }
            atomicAdd(&hist[h1], n1);
        }
        if (u2){
            uint n2 = 1;
            if (u3 && h3 == h2){ n2++; u3 = false; }
            atomicAdd(&hist[h2], n2);
        }
        if (u3) atomicAdd(&hist[h3], 1u);
    }
    __syncthreads();
    uint2 p1 = radix_scan(hist, wcnt, wbase, sh, t, lane, wv, (uint)k, 4096);
    uint B1 = p1.x; uint kk2 = (uint)k - p1.y;
    for (int i = t; i < 4096; i += 1024) hist[i] = 0u;
    __syncthreads();
    if (v0 && (c0 >> 20) == B1) atomicAdd(&hist[(c0 >> 8) & 0xFFFu], 1u);
    if (v1 && (c1 >> 20) == B1) atomicAdd(&hist[(c1 >> 8) & 0xFFFu], 1u);
    if (v2 && (c2 >> 20) == B1) atomicAdd(&hist[(c2 >> 8) & 0xFFFu], 1u);
    if (v3 && (c3 >> 20) == B1) atomicAdd(&hist[(c3 >> 8) & 0xFFFu], 1u);
    __syncthreads();
    uint2 p2 = radix_scan(hist, wcnt, wbase, sh, t, lane, wv, kk2, 4096);
    uint B2 = p2.x; uint kk3 = kk2 - p2.y;
    uint hi24 = (B1 << 12) | B2;
    for (int i = t; i < 256; i += 1024) hist[i] = 0u;
    __syncthreads();
    if (v0 && (c0 >> 8) == hi24) atomicAdd(&hist[c0 & 0xFFu], 1u);
    if (v1 && (c1 >> 8) == hi24) atomicAdd(&hist[c1 & 0xFFu], 1u);
    if (v2 && (c2 >> 8) == hi24) atomicAdd(&hist[c2 & 0xFFu], 1u);
    if (v3 && (c3 >> 8) == hi24) atomicAdd(&hist[c3 & 0xFFu], 1u);
    __syncthreads();
    uint2 p3 = radix_scan(hist, wcnt, wbase, sh, t, lane, wv, kk3, 256);
    uint T = (B1 << 20) | (B2 << 8) | p3.x;

    // --- compaction (strict > ranked, ties fill) ---------------------------
    ull b0 = __ballot(v0 && c0 > T), b1 = __ballot(v1 && c1 > T);
    ull b2 = __ballot(v2 && c2 > T), b3 = __ballot(v3 && c3 > T);
    uint t0 = (uint)__popcll(b0), t1 = (uint)__popcll(b1);
    uint t2 = (uint)__popcll(b2), t3 = (uint)__popcll(b3);
    if (lane == 0) wcnt[wv] = t0 + t1 + t2 + t3;
    __syncthreads();
    if (t == 0){
        uint s = 0;
        for (int i = 0; i < 16; i++){ wbase[i] = s; s += wcnt[i]; }
        sh[1] = s;
    }
    __syncthreads();
    uint cntGT = sh[1];
    uint rem = (uint)k - cntGT;
    ull ltm = ((ull)1 << lane) - 1;
    uint off = wbase[wv];
    if (v0 && c0 > T){ uint r = off + (uint)__popcll(b0 & ltm); int i = t;
        perm[r] = i; svals[r] = tanhf(zsh[i]); rnk[i] = (int)r; }
    off += t0;
    if (v1 && c1 > T){ uint r = off + (uint)__popcll(b1 & ltm); int i = t+1024;
        perm[r] = i; svals[r] = tanhf(zsh[i]); rnk[i] = (int)r; }
    off += t1;
    if (v2 && c2 > T){ uint r = off + (uint)__popcll(b2 & ltm); int i = t+2048;
        perm[r] = i; svals[r] = tanhf(zsh[i]); rnk[i] = (int)r; }
    off += t2;
    if (v3 && c3 > T){ uint r = off + (uint)__popcll(b3 & ltm); int i = t+3072;
        perm[r] = i; svals[r] = tanhf(zsh[i]); rnk[i] = (int)r; }
    #pragma unroll
    for (int j = 0; j < 4; j++){
        int i = t + j*1024;
        bool vv = (j==0) ? v0 : (j==1) ? v1 : (j==2) ? v2 : v3;
        uint cc = (j==0) ? c0 : (j==1) ? c1 : (j==2) ? c2 : c3;
        if (vv && cc == T){
            uint e = atomicAdd(&sh[2], 1u);
            if (e < rem){
                uint r = cntGT + e;
                perm[r] = i; svals[r] = tanhf(zsh[i]); rnk[i] = (int)r;
            }
        }
    }
    __syncthreads();
    if (slotOut >= 0){
        for (unsigned e = t; e < E; e += 1024){
            unsigned ed = eIn[e];
            int nd = rnk[ed >> 16], ns = rnk[ed & 0xFFFFu];
            if (nd >= 0 && ns >= 0){
                unsigned idx = atomicAdd(&ecnt[slotOut], 1u);
                if (idx < EDGE_CAP){
                    eOut[idx] = ((unsigned)nd << 16) | (unsigned)ns;
                    atomicAdd(&degN[nd], 1.0f);
                }
            }
        }
    }
}

// ---------------- layer-3 pool+readout (fp32-exact) + fused writeout -------
__global__ __launch_bounds__(256) void k_poolread3(const float* __restrict__ Xn,
        const int* __restrict__ perm, const float* __restrict__ svals, int k,
        uint* __restrict__ maxU, float* __restrict__ sums,
        unsigned* __restrict__ done, float* __restrict__ out){
    int b = blockIdx.x, t = threadIdx.x;
    float m = -INFINITY, s = 0.f;
    for (int r = b; r < k; r += 64){
        int p = perm[r];
        float v = Xn[p*NH + t] * svals[r];
        m = fmaxf(m, v); s += v;
    }
    atomicMax(&maxU[2*NH + t], fcode(m));
    atomicAdd(&sums[2*NH + t], s);
    __threadfence();
    __shared__ uint lastv;
    if (t == 0) lastv = atomicAdd(done, 1u);
    __syncthreads();
    if (lastv == 63u){
        // final combine; atomic loads for cross-XCD visibility
        uint m0 = atomicAdd(&maxU[t], 0u);
        uint m1 = atomicAdd(&maxU[NH + t], 0u);
        uint m2 = atomicAdd(&maxU[2*NH + t], 0u);
        float s0 = atomicAdd(&sums[t], 0.f);
        float s1v = atomicAdd(&sums[NH + t], 0.f);
        float s2 = atomicAdd(&sums[2*NH + t], 0.f);
        out[t] = fdecode(m0) + fdecode(m1) + fdecode(m2);
        out[NH + t] = s0*(1.0f/KL1) + s1v*(1.0f/KL2) + s2*(1.0f/KL3);
    }
}

// =======================================================================
extern "C" void kernel_launch(void* const* d_in, const int* in_sizes, int n_in,
                              void* d_out, int out_size, void* d_ws, size_t ws_size,
                              hipStream_t stream)
{
    const void* b1 = d_in[5];
    const void* b2 = d_in[7];
    const void* b3 = d_in[9];
    const void* Wr1 = d_in[10]; const void* Wn1 = d_in[11]; const void* bs1 = d_in[12];
    const void* Wr2 = d_in[13]; const void* Wn2 = d_in[14]; const void* bs2 = d_in[15];
    const void* Wr3 = d_in[16]; const void* Wn3 = d_in[17]; const void* bs3 = d_in[18];

    char* w = (char*)d_ws;
    auto alloc = [&](size_t bytes)->char*{ char* p = w; w += (bytes + 255) & ~(size_t)255; return p; };
    ushort*   Xb    = (ushort*)  alloc((size_t)NN*DIN*2);
    float*    Xn    = (float*)   alloc((size_t)NN*NH*4);
    float*    XW    = (float*)   alloc((size_t)NN*NH*4);
    ushort*   Wb    = (ushort*)  alloc((size_t)262144*2);
    unsigned* E0    = (unsigned*)alloc((size_t)EDGE_CAP*4);
    unsigned* E1    = (unsigned*)alloc((size_t)EDGE_CAP*4);
    float*    tmin  = (float*)   alloc(4096*4);
    float*    sq    = (float*)   alloc(NN*4);
    float*    degA  = (float*)   alloc(NN*4);
    float*    degB  = (float*)   alloc(NN*4);
    float*    s1    = (float*)   alloc(NN*4);
    float*    z     = (float*)   alloc(NN*4);
    int*      perm  = (int*)     alloc(NN*4);
    float*    svals = (float*)   alloc(NN*4);
    unsigned* ecnt  = (unsigned*)alloc(256);
    unsigned* maxd2 = (unsigned*)alloc(256);
    unsigned* dflag = (unsigned*)alloc(256);
    uint*     maxU  = (uint*)    alloc(768*4);
    float*    sums  = (float*)   alloc(768*4);
    (void)ws_size;

    DtIn da;
    for (int i = 0; i < 19; i++){ da.p[i] = d_in[i]; da.n[i] = in_sizes[i]; }

    k_prep<<<NN + 65, 512, 0, stream>>>(da, Xb, sq, Wb, dflag, degA, maxU, sums,
            ecnt, maxd2, tmin);
    // gram pass 1: 128 fused XW tiles (128x64) + 528 triangle tiles (128x128)
    k_gram<1><<<128 + NT128, 512, 0, stream>>>(Xb, sq, maxd2, tmin, ecnt, E0, degA,
            Wb, XW);
    k_gram<2><<<NT128, 512, 0, stream>>>(Xb, sq, maxd2, tmin, ecnt, E0, degA,
            Wb, XW);

    // ---------------- layer 1 (N=4096 -> k=3072) ----------------
    k_gcnscore<<<NN, 256, 0, stream>>>(XW, E0, ecnt, 0, degA, b1, Wn1, Wr1, bs1,
            dflag+5, dflag+11, dflag+10, dflag+12, Xn, s1, z);
    k_select<<<1, 1024, 0, stream>>>(z, s1, NN, KL1, E0, ecnt, 0, E1, 1,
            perm, svals, degB, KL1);

    // ---------------- layer 2 (N=3072 -> k=2304); fused pool1+readout ------
    k_xwp<<<dim3(48,4), 256, 0, stream>>>(Xn, perm, svals, Wb + 131072, XW, KL1,
            maxU, sums, 0);
    k_gcnscore<<<KL1, 256, 0, stream>>>(XW, E1, ecnt, 1, degB, b2, Wn2, Wr2, bs2,
            dflag+7, dflag+14, dflag+13, dflag+15, Xn, s1, z);
    k_select<<<1, 1024, 0, stream>>>(z, s1, KL1, KL2, E1, ecnt, 1, E0, 2,
            perm, svals, degA, KL2);

    // ---------------- layer 3 (N=2304 -> k=1728); fused pool2+readout ------
    k_xwp<<<dim3(36,4), 256, 0, stream>>>(Xn, perm, svals, Wb + 196608, XW, KL2,
            maxU, sums, 1);
    k_gcnscore<<<KL2, 256, 0, stream>>>(XW, E0, ecnt, 2, degA, b3, Wn3, Wr3, bs3,
            dflag+9, dflag+17, dflag+16, dflag+18, Xn, s1, z);
    k_select<<<1, 1024, 0, stream>>>(z, s1, KL2, KL3, E0, ecnt, 2,
            (unsigned*)nullptr, -1, perm, svals, degB, 0);
    k_poolread3<<<64, 256, 0, stream>>>(Xn, perm, svals, KL3, maxU, sums,
            ecnt + 3, (float*)d_out);
}